// Round 1
// 687.579 us; speedup vs baseline: 2.0802x; 2.0802x over previous
//
#include <hip/hip_runtime.h>

#define N_USERS 50000
#define N_ENT   150000
#define N_NODES 200000
#define NE      2000000
#define BATCH   8192
#define NB 782          // ceil(N_NODES / 256)

typedef __attribute__((ext_vector_type(8))) short   bf16x8;
typedef __attribute__((ext_vector_type(4))) float   f32x4;

__device__ __forceinline__ float bf2f(unsigned short b) {
    return __uint_as_float(((unsigned int)b) << 16);
}
__device__ __forceinline__ unsigned short f2bf(float f) {
    unsigned int u = __float_as_uint(f);
    u += 0x7FFF + ((u >> 16) & 1);          // round-to-nearest-even
    return (unsigned short)(u >> 16);
}

// ===========================================================================
// CSR build: histogram -> exclusive scan -> atomic-cursor fill.
// After fill, rs[r] == row_end; row_start = rs[r] - deg[r].
// ===========================================================================
__global__ __launch_bounds__(256) void hist_kernel(const int* __restrict__ rows,
                                                   int* __restrict__ deg) {
    int e = blockIdx.x * 256 + threadIdx.x;
    if (e < NE) atomicAdd(&deg[rows[e]], 1);
}

__global__ __launch_bounds__(256) void scan1(const int* __restrict__ deg,
                                             int* __restrict__ rs,
                                             int* __restrict__ blk) {
    __shared__ int buf[256];
    int i = blockIdx.x * 256 + threadIdx.x;
    int v = (i < N_NODES) ? deg[i] : 0;
    buf[threadIdx.x] = v;
    __syncthreads();
    for (int off = 1; off < 256; off <<= 1) {
        int x = (threadIdx.x >= off) ? buf[threadIdx.x - off] : 0;
        __syncthreads();
        buf[threadIdx.x] += x;
        __syncthreads();
    }
    if (i < N_NODES) rs[i] = buf[threadIdx.x] - v;       // exclusive
    if (threadIdx.x == 255) blk[blockIdx.x] = buf[255];
}

__global__ __launch_bounds__(1024) void scan2(int* __restrict__ blk) {
    __shared__ int buf[1024];
    int t = threadIdx.x;
    int v = (t < NB) ? blk[t] : 0;
    buf[t] = v;
    __syncthreads();
    for (int off = 1; off < 1024; off <<= 1) {
        int x = (t >= off) ? buf[t - off] : 0;
        __syncthreads();
        buf[t] += x;
        __syncthreads();
    }
    if (t < NB) blk[t] = buf[t] - v;
}

__global__ __launch_bounds__(256) void scan3(int* __restrict__ rs,
                                             const int* __restrict__ blk) {
    int i = blockIdx.x * 256 + threadIdx.x;
    if (i < N_NODES) rs[i] += blk[blockIdx.x];
}

__global__ __launch_bounds__(256) void fill_kernel(const int* __restrict__ rows,
                                                   const int* __restrict__ cols,
                                                   const float* __restrict__ vals,
                                                   int* __restrict__ rs,
                                                   int* __restrict__ ccol,
                                                   float* __restrict__ cval) {
    int e = blockIdx.x * 256 + threadIdx.x;
    if (e >= NE) return;
    int pos = atomicAdd(&rs[rows[e]], 1);
    ccol[pos] = cols[e];
    cval[pos] = vals[e];
}

// ---------------------------------------------------------------------------
// t0 = bf16(concat(ue, ee)) — the layer-0 gather table (one 128 B line/row).
// ---------------------------------------------------------------------------
__global__ __launch_bounds__(256) void build_t0(const float* __restrict__ ue,
                                                const float* __restrict__ ee,
                                                unsigned short* __restrict__ t0) {
    int i = blockIdx.x * 256 + threadIdx.x;              // float4 index
    const int total = N_NODES * 64 / 4;
    if (i >= total) return;
    const int uelems = N_USERS * 64 / 4;
    float4 v = (i < uelems) ? ((const float4*)ue)[i]
                            : ((const float4*)ee)[i - uelems];
    ushort4 o;
    o.x = f2bf(v.x); o.y = f2bf(v.y); o.z = f2bf(v.z); o.w = f2bf(v.w);
    ((ushort4*)t0)[i] = o;
}

// ---------------------------------------------------------------------------
// Pre-transpose weights to bf16 [n][k] (k contiguous) so MFMA B-fragments are
// contiguous 16 B loads. Single launch covering all 6 matrices.
// Layout in wt (ushort units): wg0T@0 wb0T@4096 wg1T@8192 wb1T@10240
//                              wg2T@12288 wb2T@12800 (total 13312)
// ---------------------------------------------------------------------------
__global__ __launch_bounds__(256) void prep_wt(
        const float* __restrict__ Wg0, const float* __restrict__ Wb0,
        const float* __restrict__ Wg1, const float* __restrict__ Wb1,
        const float* __restrict__ Wg2, const float* __restrict__ Wb2,
        unsigned short* __restrict__ wt) {
    int idx = blockIdx.x * 256 + threadIdx.x;
    if (idx < 4096) {                       // Wg0: 64x64
        int k = idx >> 6, n = idx & 63;
        wt[0 + n * 64 + k] = f2bf(Wg0[idx]);
    } else if (idx < 8192) {                // Wb0: 64x64
        int r = idx - 4096; int k = r >> 6, n = r & 63;
        wt[4096 + n * 64 + k] = f2bf(Wb0[r]);
    } else if (idx < 10240) {               // Wg1: 64x32
        int r = idx - 8192; int k = r >> 5, n = r & 31;
        wt[8192 + n * 64 + k] = f2bf(Wg1[r]);
    } else if (idx < 12288) {               // Wb1: 64x32
        int r = idx - 10240; int k = r >> 5, n = r & 31;
        wt[10240 + n * 64 + k] = f2bf(Wb1[r]);
    } else if (idx < 12800) {               // Wg2: 32x16
        int r = idx - 12288; int k = r >> 4, n = r & 15;
        wt[12288 + n * 32 + k] = f2bf(Wg2[r]);
    } else if (idx < 13312) {               // Wb2: 32x16
        int r = idx - 12800; int k = r >> 4, n = r & 15;
        wt[12800 + n * 32 + k] = f2bf(Wb2[r]);
    }
}

// ===========================================================================
// Pass 1: CSR gather, wave per row, ZERO LDS / ZERO shuffles on the hot path.
// row is forced to SGPR (readfirstlane) so rs/deg/ccol/cval become scalar
// (SMEM) loads; gathers are wave-coalesced 128 B line reads of the bf16
// table. Emits H = e + side and P = e * side as bf16 (MFMA A-operands).
// EGO: 0 = ue/ee fp32 (layer0), 1 = xin fp32 (layer1), 2 = tin bf16 (layer2).
// Pad slots read in-workspace garbage (ccol overrun lands in deg[] => valid
// small row ids; clamped anyway) and are multiplied by v=0.
// ===========================================================================
template <int DIN, int EGO>
__global__ __launch_bounds__(256) void gather_hp(
        const int* __restrict__ rs, const int* __restrict__ deg,
        const int* __restrict__ ccol, const float* __restrict__ cval,
        const unsigned short* __restrict__ tin,
        const float* __restrict__ ue, const float* __restrict__ ee,
        const float* __restrict__ xin,
        unsigned short* __restrict__ Hout,
        unsigned short* __restrict__ Pout) {
    const int lane  = threadIdx.x & 63;
    const int row_v = (blockIdx.x * 256 + threadIdx.x) >> 6;
    const int row   = __builtin_amdgcn_readfirstlane(row_v);
    const int end   = rs[row];
    const int start = end - deg[row];

    float acc;
    if (DIN == 64) {
        float a0 = 0.f, a1 = 0.f, a2 = 0.f, a3 = 0.f;
        for (int i = start; i < end; i += 4) {
            int   c0 = ccol[i + 0], c1 = ccol[i + 1];
            int   c2 = ccol[i + 2], c3 = ccol[i + 3];
            float v0 = cval[i + 0], v1 = cval[i + 1];
            float v2 = cval[i + 2], v3 = cval[i + 3];
            v1 = (i + 1 < end) ? v1 : 0.f;
            v2 = (i + 2 < end) ? v2 : 0.f;
            v3 = (i + 3 < end) ? v3 : 0.f;
            c1 = (c1 < N_NODES) ? c1 : 0;
            c2 = (c2 < N_NODES) ? c2 : 0;
            c3 = (c3 < N_NODES) ? c3 : 0;
            a0 = fmaf(v0, bf2f(tin[(size_t)c0 * 64 + lane]), a0);
            a1 = fmaf(v1, bf2f(tin[(size_t)c1 * 64 + lane]), a1);
            a2 = fmaf(v2, bf2f(tin[(size_t)c2 * 64 + lane]), a2);
            a3 = fmaf(v3, bf2f(tin[(size_t)c3 * 64 + lane]), a3);
        }
        acc = (a0 + a1) + (a2 + a3);
    } else {   // DIN == 32: two half-waves split the edge list (4 edges each)
        const int g = lane >> 5;
        const int d = lane & 31;
        float a0 = 0.f, a1 = 0.f, a2 = 0.f, a3 = 0.f;
        for (int i = start; i < end; i += 8) {
            int   c0 = ccol[i + 0], c1 = ccol[i + 1], c2 = ccol[i + 2], c3 = ccol[i + 3];
            int   c4 = ccol[i + 4], c5 = ccol[i + 5], c6 = ccol[i + 6], c7 = ccol[i + 7];
            float v0 = cval[i + 0], v1 = cval[i + 1], v2 = cval[i + 2], v3 = cval[i + 3];
            float v4 = cval[i + 4], v5 = cval[i + 5], v6 = cval[i + 6], v7 = cval[i + 7];
            v1 = (i + 1 < end) ? v1 : 0.f;  c1 = (c1 < N_NODES) ? c1 : 0;
            v2 = (i + 2 < end) ? v2 : 0.f;  c2 = (c2 < N_NODES) ? c2 : 0;
            v3 = (i + 3 < end) ? v3 : 0.f;  c3 = (c3 < N_NODES) ? c3 : 0;
            v4 = (i + 4 < end) ? v4 : 0.f;  c4 = (c4 < N_NODES) ? c4 : 0;
            v5 = (i + 5 < end) ? v5 : 0.f;  c5 = (c5 < N_NODES) ? c5 : 0;
            v6 = (i + 6 < end) ? v6 : 0.f;  c6 = (c6 < N_NODES) ? c6 : 0;
            v7 = (i + 7 < end) ? v7 : 0.f;  c7 = (c7 < N_NODES) ? c7 : 0;
            int   ca = g ? c4 : c0;  float va = g ? v4 : v0;
            int   cb = g ? c5 : c1;  float vb = g ? v5 : v1;
            int   cc = g ? c6 : c2;  float vc = g ? v6 : v2;
            int   cd = g ? c7 : c3;  float vd = g ? v7 : v3;
            a0 = fmaf(va, bf2f(tin[(size_t)ca * 32 + d]), a0);
            a1 = fmaf(vb, bf2f(tin[(size_t)cb * 32 + d]), a1);
            a2 = fmaf(vc, bf2f(tin[(size_t)cc * 32 + d]), a2);
            a3 = fmaf(vd, bf2f(tin[(size_t)cd * 32 + d]), a3);
        }
        acc = (a0 + a1) + (a2 + a3);
        acc += __shfl_xor(acc, 32);      // combine the two half-waves
    }

    // own ego value
    const int d = (DIN == 64) ? lane : (lane & 31);
    float e;
    if (EGO == 0) {
        e = (row < N_USERS) ? ue[(size_t)row * 64 + lane]
                            : ee[(size_t)(row - N_USERS) * 64 + lane];
    } else if (EGO == 1) {
        e = xin[(size_t)row * DIN + lane];
    } else {
        e = bf2f(tin[(size_t)row * DIN + d]);
    }
    float h = e + acc;
    float p = e * acc;
    if (DIN == 64 || lane < 32) {
        Hout[(size_t)row * DIN + d] = f2bf(h);
        Pout[(size_t)row * DIN + d] = f2bf(p);
    }
}

// ===========================================================================
// Pass 2: dense transform via MFMA. Block 256 = 4 waves, each wave owns 16
// rows; out = leaky(H@Wg+bg) + leaky(P@Wb+bb); writes bf16 tout (next gather
// table / scoring) [+ fp32 xout if WX] and the per-row L2 norm.
// mfma_f32_16x16x32_bf16 layouts: A[row=l&15][k=(l>>4)*8+j],
// B[k=(l>>4)*8+j][col=l&15], D col=l&15, row=(l>>4)*4+reg (m89-verified).
// ===========================================================================
template <int K, int NOUT, int WX>
__global__ __launch_bounds__(256) void transform_mfma(
        const unsigned short* __restrict__ H,
        const unsigned short* __restrict__ P,
        const unsigned short* __restrict__ WgT,   // bf16 [NOUT][K]
        const unsigned short* __restrict__ WbT,
        const float* __restrict__ bg, const float* __restrict__ bb,
        float* __restrict__ xout,                 // fp32 [N][NOUT] (if WX)
        unsigned short* __restrict__ tout,        // bf16 [N][NOUT]
        float* __restrict__ norm_out) {
    constexpr int NT = NOUT / 16;
    constexpr int KS = K / 32;
    const int lane    = threadIdx.x & 63;
    const int wave    = threadIdx.x >> 6;
    const int rowbase = blockIdx.x * 64 + wave * 16;
    const int r16 = lane & 15;
    const int g4  = lane >> 4;

    // A fragments (16 rows x K, bf16, contiguous 16 B per lane)
    bf16x8 ah[KS], ap[KS];
    const size_t arow = (size_t)(rowbase + r16) * K + g4 * 8;
#pragma unroll
    for (int s = 0; s < KS; ++s) {
        ah[s] = *reinterpret_cast<const bf16x8*>(H + arow + s * 32);
        ap[s] = *reinterpret_cast<const bf16x8*>(P + arow + s * 32);
    }

    f32x4 accg[NT], accb[NT];
#pragma unroll
    for (int t = 0; t < NT; ++t) {
        accg[t] = (f32x4){0.f, 0.f, 0.f, 0.f};
        accb[t] = (f32x4){0.f, 0.f, 0.f, 0.f};
    }
#pragma unroll
    for (int t = 0; t < NT; ++t) {
        const size_t brow = (size_t)(t * 16 + r16) * K + g4 * 8;
#pragma unroll
        for (int s = 0; s < KS; ++s) {
            bf16x8 bgf = *reinterpret_cast<const bf16x8*>(WgT + brow + s * 32);
            bf16x8 bbf = *reinterpret_cast<const bf16x8*>(WbT + brow + s * 32);
            accg[t] = __builtin_amdgcn_mfma_f32_16x16x32_bf16(ah[s], bgf, accg[t], 0, 0, 0);
            accb[t] = __builtin_amdgcn_mfma_f32_16x16x32_bf16(ap[s], bbf, accb[t], 0, 0, 0);
        }
    }

    // epilogue: bias + leaky + sum, stores, per-row norm
    float ss0 = 0.f, ss1 = 0.f, ss2 = 0.f, ss3 = 0.f;
#pragma unroll
    for (int t = 0; t < NT; ++t) {
        const int col = t * 16 + r16;
        const float bgv = bg[col];
        const float bbv = bb[col];
#pragma unroll
        for (int r = 0; r < 4; ++r) {
            float a = accg[t][r] + bgv; a = a > 0.f ? a : 0.01f * a;
            float b = accb[t][r] + bbv; b = b > 0.f ? b : 0.01f * b;
            float nv = a + b;
            const int row = rowbase + g4 * 4 + r;
            if (WX) xout[(size_t)row * NOUT + col] = nv;
            tout[(size_t)row * NOUT + col] = f2bf(nv);
            if (r == 0) ss0 += nv * nv;
            if (r == 1) ss1 += nv * nv;
            if (r == 2) ss2 += nv * nv;
            if (r == 3) ss3 += nv * nv;
        }
    }
#pragma unroll
    for (int off = 1; off < 16; off <<= 1) {
        ss0 += __shfl_xor(ss0, off);
        ss1 += __shfl_xor(ss1, off);
        ss2 += __shfl_xor(ss2, off);
        ss3 += __shfl_xor(ss3, off);
    }
    float sv = ss0;
    sv = (r16 == 1) ? ss1 : sv;
    sv = (r16 == 2) ? ss2 : sv;
    sv = (r16 == 3) ? ss3 : sv;
    if (r16 < 4) norm_out[rowbase + g4 * 4 + r16] = fmaxf(sqrtf(sv), 1e-12f);
}

// ===========================================================================
// Scoring: one wave per batch element; sections 64 raw + 64 (e1 fp32) +
// 32 (t2 bf16) + 16 (t3 bf16); normalization folded as 1/(norm products).
// ===========================================================================
__global__ __launch_bounds__(256) void score_kernel(
        const int* __restrict__ users, const int* __restrict__ pos,
        const int* __restrict__ neg,
        const float* __restrict__ ue, const float* __restrict__ ee,
        const float* __restrict__ e1, const float* __restrict__ n0,
        const unsigned short* __restrict__ t2, const float* __restrict__ n1,
        const unsigned short* __restrict__ t3, const float* __restrict__ n2,
        float* __restrict__ out) {
    int gid  = blockIdx.x * 256 + threadIdx.x;
    int idx  = gid >> 6;
    int lane = gid & 63;
    if (idx >= BATCH) return;
    int u  = users[idx];
    int pe = pos[idx];
    int ne = neg[idx];
    int pn = N_USERS + pe;
    int nn = N_USERS + ne;

    float s1p = 1.0f / (n0[u] * n0[pn]);
    float s1n = 1.0f / (n0[u] * n0[nn]);
    float s2p = 1.0f / (n1[u] * n1[pn]);
    float s2n = 1.0f / (n1[u] * n1[nn]);
    float s3p = 1.0f / (n2[u] * n2[pn]);
    float s3n = 1.0f / (n2[u] * n2[nn]);

    float ap = 0.f, an = 0.f;
    {
        float xu = ue[(size_t)u * 64 + lane];
        ap += xu * ee[(size_t)pe * 64 + lane];
        an += xu * ee[(size_t)ne * 64 + lane];
    }
    {
        float xu = e1[(size_t)u * 64 + lane];
        ap += xu * e1[(size_t)pn * 64 + lane] * s1p;
        an += xu * e1[(size_t)nn * 64 + lane] * s1n;
    }
    if (lane < 32) {
        float xu = bf2f(t2[(size_t)u * 32 + lane]);
        ap += xu * bf2f(t2[(size_t)pn * 32 + lane]) * s2p;
        an += xu * bf2f(t2[(size_t)nn * 32 + lane]) * s2n;
    } else if (lane < 48) {
        int d = lane - 32;
        float xu = bf2f(t3[(size_t)u * 16 + d]);
        ap += xu * bf2f(t3[(size_t)pn * 16 + d]) * s3p;
        an += xu * bf2f(t3[(size_t)nn * 16 + d]) * s3n;
    }
#pragma unroll
    for (int off = 32; off > 0; off >>= 1) {
        ap += __shfl_xor(ap, off);
        an += __shfl_xor(an, off);
    }
    if (lane == 0) {
        out[2 * idx + 0] = ap;
        out[2 * idx + 1] = an;
    }
}

// ===========================================================================
extern "C" void kernel_launch(void* const* d_in, const int* in_sizes, int n_in,
                              void* d_out, int out_size, void* d_ws, size_t ws_size,
                              hipStream_t stream) {
    const int*   users = (const int*)d_in[0];
    const int*   pos   = (const int*)d_in[1];
    const int*   neg   = (const int*)d_in[2];
    const int*   rows  = (const int*)d_in[3];
    const int*   cols  = (const int*)d_in[4];
    const float* vals  = (const float*)d_in[5];
    const float* ue    = (const float*)d_in[6];
    const float* ee    = (const float*)d_in[7];
    const float* Wg0 = (const float*)d_in[8],  *bg0 = (const float*)d_in[9];
    const float* Wb0 = (const float*)d_in[10], *bb0 = (const float*)d_in[11];
    const float* Wg1 = (const float*)d_in[12], *bg1 = (const float*)d_in[13];
    const float* Wb1 = (const float*)d_in[14], *bb1 = (const float*)d_in[15];
    const float* Wg2 = (const float*)d_in[16], *bg2 = (const float*)d_in[17];
    const float* Wb2 = (const float*)d_in[18], *bb2 = (const float*)d_in[19];

    // workspace (~180 MB; >=192 MB proven available)
    float* e1   = (float*)d_ws;                          // N x 64 fp32 (unnorm L1 out)
    float* n0   = e1 + (size_t)N_NODES * 64;             // N
    float* n1   = n0 + N_NODES;                          // N
    float* n2   = n1 + N_NODES;                          // N
    float* cval = n2 + N_NODES;                          // E
    unsigned short* tA = (unsigned short*)(cval + NE);   // N x 64 bf16 (t0, then t2)
    unsigned short* tB = tA + (size_t)N_NODES * 64;      // N x 64 bf16 (t1)
    unsigned short* t3 = tB + (size_t)N_NODES * 64;      // N x 16 bf16 (L3 out)
    unsigned short* Hb = t3 + (size_t)N_NODES * 16;      // N x 64 bf16
    unsigned short* Pb = Hb + (size_t)N_NODES * 64;      // N x 64 bf16
    unsigned short* wt = Pb + (size_t)N_NODES * 64;      // 13312 (transposed weights)
    int* ccol = (int*)(wt + 13312);                      // E  (immediately after wt:
    int* deg  = ccol + NE;                               //  ccol overrun lands in deg)
    int* rs   = deg + N_NODES;                           // N
    int* blk  = rs + N_NODES;                            // 1024

    // ---- CSR build + bf16 layer-0 table + weight transpose (once) ----
    hipMemsetAsync(deg, 0, N_NODES * sizeof(int), stream);
    hist_kernel<<<(NE + 255) / 256, 256, 0, stream>>>(rows, deg);
    scan1<<<NB, 256, 0, stream>>>(deg, rs, blk);
    scan2<<<1, 1024, 0, stream>>>(blk);
    scan3<<<NB, 256, 0, stream>>>(rs, blk);
    fill_kernel<<<(NE + 255) / 256, 256, 0, stream>>>(rows, cols, vals, rs, ccol, cval);
    build_t0<<<(N_NODES * 64 / 4 + 255) / 256, 256, 0, stream>>>(ue, ee, tA);
    prep_wt<<<(13312 + 255) / 256, 256, 0, stream>>>(Wg0, Wb0, Wg1, Wb1, Wg2, Wb2, wt);

    // ---- 3 layers: scalar-CSR gather pass + MFMA transform pass ----
    const int ggrid = N_NODES * 64 / 256;   // 50000, wave per row
    const int tgrid = N_NODES / 64;         // 3125, 16 rows per wave

    gather_hp<64, 0><<<ggrid, 256, 0, stream>>>(rs, deg, ccol, cval, tA,
                                                ue, ee, nullptr, Hb, Pb);
    transform_mfma<64, 64, 1><<<tgrid, 256, 0, stream>>>(Hb, Pb, wt, wt + 4096,
                                                         bg0, bb0, e1, tB, n0);
    gather_hp<64, 1><<<ggrid, 256, 0, stream>>>(rs, deg, ccol, cval, tB,
                                                ue, ee, e1, Hb, Pb);
    transform_mfma<64, 32, 0><<<tgrid, 256, 0, stream>>>(Hb, Pb, wt + 8192, wt + 10240,
                                                         bg1, bb1, nullptr, tA, n1);
    gather_hp<32, 2><<<ggrid, 256, 0, stream>>>(rs, deg, ccol, cval, tA,
                                                ue, ee, nullptr, Hb, Pb);
    transform_mfma<32, 16, 0><<<tgrid, 256, 0, stream>>>(Hb, Pb, wt + 12288, wt + 12800,
                                                         bg2, bb2, nullptr, t3, n2);

    // ---- scoring ----
    score_kernel<<<(BATCH * 64) / 256, 256, 0, stream>>>(users, pos, neg, ue, ee,
                                                         e1, n0, tA, n1, t3, n2,
                                                         (float*)d_out);
}

// Round 2
// 666.880 us; speedup vs baseline: 2.1448x; 1.0310x over previous
//
#include <hip/hip_runtime.h>

#define N_USERS 50000
#define N_ENT   150000
#define N_NODES 200000
#define NE      2000000
#define BATCH   8192
#define NB 782          // ceil(N_NODES / 256)

typedef __attribute__((ext_vector_type(8))) short   bf16x8;
typedef __attribute__((ext_vector_type(4))) float   f32x4;

__device__ __forceinline__ float bf2f(unsigned short b) {
    return __uint_as_float(((unsigned int)b) << 16);
}
__device__ __forceinline__ unsigned short f2bf(float f) {
    unsigned int u = __float_as_uint(f);
    u += 0x7FFF + ((u >> 16) & 1);          // round-to-nearest-even
    return (unsigned short)(u >> 16);
}

// ===========================================================================
// CSR build: histogram -> exclusive scan -> atomic-cursor fill.
// After fill, rs[r] == row_end; row_start = rs[r] - deg[r].
// Edge records packed as uint2 {col, val_bits}: ONE 8 B scatter store per
// edge (was two 4 B stores to two arrays -> 194 MB write-amp, 134 us).
// ===========================================================================
__global__ __launch_bounds__(256) void hist_kernel(const int4* __restrict__ rows4,
                                                   int* __restrict__ deg) {
    int i = blockIdx.x * 256 + threadIdx.x;
    if (i < NE / 4) {
        int4 r = rows4[i];
        atomicAdd(&deg[r.x], 1);
        atomicAdd(&deg[r.y], 1);
        atomicAdd(&deg[r.z], 1);
        atomicAdd(&deg[r.w], 1);
    }
}

__global__ __launch_bounds__(256) void scan1(const int* __restrict__ deg,
                                             int* __restrict__ rs,
                                             int* __restrict__ blk) {
    __shared__ int buf[256];
    int i = blockIdx.x * 256 + threadIdx.x;
    int v = (i < N_NODES) ? deg[i] : 0;
    buf[threadIdx.x] = v;
    __syncthreads();
    for (int off = 1; off < 256; off <<= 1) {
        int x = (threadIdx.x >= off) ? buf[threadIdx.x - off] : 0;
        __syncthreads();
        buf[threadIdx.x] += x;
        __syncthreads();
    }
    if (i < N_NODES) rs[i] = buf[threadIdx.x] - v;       // exclusive
    if (threadIdx.x == 255) blk[blockIdx.x] = buf[255];
}

__global__ __launch_bounds__(1024) void scan2(int* __restrict__ blk) {
    __shared__ int buf[1024];
    int t = threadIdx.x;
    int v = (t < NB) ? blk[t] : 0;
    buf[t] = v;
    __syncthreads();
    for (int off = 1; off < 1024; off <<= 1) {
        int x = (t >= off) ? buf[t - off] : 0;
        __syncthreads();
        buf[t] += x;
        __syncthreads();
    }
    if (t < NB) blk[t] = buf[t] - v;
}

__global__ __launch_bounds__(256) void scan3(int* __restrict__ rs,
                                             const int* __restrict__ blk) {
    int i = blockIdx.x * 256 + threadIdx.x;
    if (i < N_NODES) rs[i] += blk[blockIdx.x];
}

__global__ __launch_bounds__(256) void fill_kernel(const int* __restrict__ rows,
                                                   const int* __restrict__ cols,
                                                   const float* __restrict__ vals,
                                                   int* __restrict__ rs,
                                                   uint2* __restrict__ ep) {
    int e = blockIdx.x * 256 + threadIdx.x;
    if (e >= NE) return;
    int pos = atomicAdd(&rs[rows[e]], 1);
    uint2 rec;
    rec.x = (unsigned int)cols[e];
    rec.y = __float_as_uint(vals[e]);
    ep[pos] = rec;                          // single 8 B scatter
}

// ---------------------------------------------------------------------------
// t0 = bf16(concat(ue, ee)) — the layer-0 gather table (one 128 B line/row).
// ---------------------------------------------------------------------------
__global__ __launch_bounds__(256) void build_t0(const float* __restrict__ ue,
                                                const float* __restrict__ ee,
                                                unsigned short* __restrict__ t0) {
    int i = blockIdx.x * 256 + threadIdx.x;              // float4 index
    const int total = N_NODES * 64 / 4;
    if (i >= total) return;
    const int uelems = N_USERS * 64 / 4;
    float4 v = (i < uelems) ? ((const float4*)ue)[i]
                            : ((const float4*)ee)[i - uelems];
    ushort4 o;
    o.x = f2bf(v.x); o.y = f2bf(v.y); o.z = f2bf(v.z); o.w = f2bf(v.w);
    ((ushort4*)t0)[i] = o;
}

// ---------------------------------------------------------------------------
// Pre-transpose weights to bf16 [n][k] (k contiguous) so MFMA B-fragments are
// contiguous 16 B loads. Layout in wt (ushort units): wg0T@0 wb0T@4096
// wg1T@8192 wb1T@10240 wg2T@12288 wb2T@12800 (total 13312)
// ---------------------------------------------------------------------------
__global__ __launch_bounds__(256) void prep_wt(
        const float* __restrict__ Wg0, const float* __restrict__ Wb0,
        const float* __restrict__ Wg1, const float* __restrict__ Wb1,
        const float* __restrict__ Wg2, const float* __restrict__ Wb2,
        unsigned short* __restrict__ wt) {
    int idx = blockIdx.x * 256 + threadIdx.x;
    if (idx < 4096) {                       // Wg0: 64x64
        int k = idx >> 6, n = idx & 63;
        wt[0 + n * 64 + k] = f2bf(Wg0[idx]);
    } else if (idx < 8192) {                // Wb0: 64x64
        int r = idx - 4096; int k = r >> 6, n = r & 63;
        wt[4096 + n * 64 + k] = f2bf(Wb0[r]);
    } else if (idx < 10240) {               // Wg1: 64x32
        int r = idx - 8192; int k = r >> 5, n = r & 31;
        wt[8192 + n * 64 + k] = f2bf(Wg1[r]);
    } else if (idx < 12288) {               // Wb1: 64x32
        int r = idx - 10240; int k = r >> 5, n = r & 31;
        wt[10240 + n * 64 + k] = f2bf(Wb1[r]);
    } else if (idx < 12800) {               // Wg2: 32x16
        int r = idx - 12288; int k = r >> 4, n = r & 15;
        wt[12288 + n * 32 + k] = f2bf(Wg2[r]);
    } else if (idx < 13312) {               // Wb2: 32x16
        int r = idx - 12800; int k = r >> 4, n = r & 15;
        wt[12800 + n * 32 + k] = f2bf(Wb2[r]);
    }
}

// ===========================================================================
// Pass 1: CSR gather, wave per row, ZERO LDS / ZERO shuffles on the hot path.
// row is forced to SGPR (readfirstlane) so rs/deg/ep become scalar (SMEM)
// loads; gathers are wave-coalesced 128 B line reads of the bf16 table.
// Emits H = e + side and P = e * side as bf16 (MFMA A-operands).
// EGO: 0 = ue/ee fp32 (layer0), 1 = xin fp32 (layer1), 2 = tin bf16 (layer2).
// Tail slots may read garbage records past row end (lands in the bf16 table
// region) -> UNSIGNED clamp of col, v forced to 0 so fma adds 0.
// ===========================================================================
template <int DIN, int EGO>
__global__ __launch_bounds__(256) void gather_hp(
        const int* __restrict__ rs, const int* __restrict__ deg,
        const uint2* __restrict__ ep,
        const unsigned short* __restrict__ tin,
        const float* __restrict__ ue, const float* __restrict__ ee,
        const float* __restrict__ xin,
        unsigned short* __restrict__ Hout,
        unsigned short* __restrict__ Pout) {
    const int lane  = threadIdx.x & 63;
    const int row_v = (blockIdx.x * 256 + threadIdx.x) >> 6;
    const int row   = __builtin_amdgcn_readfirstlane(row_v);
    const int end   = rs[row];
    const int start = end - deg[row];

    float acc;
    if (DIN == 64) {
        float a0 = 0.f, a1 = 0.f, a2 = 0.f, a3 = 0.f;
        for (int i = start; i < end; i += 4) {
            uint2 r0 = ep[i + 0];
            uint2 r1 = ep[i + 1];
            uint2 r2 = ep[i + 2];
            uint2 r3 = ep[i + 3];
            int c0 = (int)r0.x;
            int c1 = ((unsigned)r1.x < N_NODES) ? (int)r1.x : 0;
            int c2 = ((unsigned)r2.x < N_NODES) ? (int)r2.x : 0;
            int c3 = ((unsigned)r3.x < N_NODES) ? (int)r3.x : 0;
            float v0 = __uint_as_float(r0.y);
            float v1 = (i + 1 < end) ? __uint_as_float(r1.y) : 0.f;
            float v2 = (i + 2 < end) ? __uint_as_float(r2.y) : 0.f;
            float v3 = (i + 3 < end) ? __uint_as_float(r3.y) : 0.f;
            a0 = fmaf(v0, bf2f(tin[(size_t)c0 * 64 + lane]), a0);
            a1 = fmaf(v1, bf2f(tin[(size_t)c1 * 64 + lane]), a1);
            a2 = fmaf(v2, bf2f(tin[(size_t)c2 * 64 + lane]), a2);
            a3 = fmaf(v3, bf2f(tin[(size_t)c3 * 64 + lane]), a3);
        }
        acc = (a0 + a1) + (a2 + a3);
    } else {   // DIN == 32: two half-waves split the edge list (4 edges each)
        const int g = lane >> 5;
        const int d = lane & 31;
        float a0 = 0.f, a1 = 0.f, a2 = 0.f, a3 = 0.f;
        for (int i = start; i < end; i += 8) {
            uint2 r0 = ep[i + 0], r1 = ep[i + 1], r2 = ep[i + 2], r3 = ep[i + 3];
            uint2 r4 = ep[i + 4], r5 = ep[i + 5], r6 = ep[i + 6], r7 = ep[i + 7];
            int c0 = (int)r0.x;
            int c1 = ((unsigned)r1.x < N_NODES) ? (int)r1.x : 0;
            int c2 = ((unsigned)r2.x < N_NODES) ? (int)r2.x : 0;
            int c3 = ((unsigned)r3.x < N_NODES) ? (int)r3.x : 0;
            int c4 = ((unsigned)r4.x < N_NODES) ? (int)r4.x : 0;
            int c5 = ((unsigned)r5.x < N_NODES) ? (int)r5.x : 0;
            int c6 = ((unsigned)r6.x < N_NODES) ? (int)r6.x : 0;
            int c7 = ((unsigned)r7.x < N_NODES) ? (int)r7.x : 0;
            float v0 = __uint_as_float(r0.y);
            float v1 = (i + 1 < end) ? __uint_as_float(r1.y) : 0.f;
            float v2 = (i + 2 < end) ? __uint_as_float(r2.y) : 0.f;
            float v3 = (i + 3 < end) ? __uint_as_float(r3.y) : 0.f;
            float v4 = (i + 4 < end) ? __uint_as_float(r4.y) : 0.f;
            float v5 = (i + 5 < end) ? __uint_as_float(r5.y) : 0.f;
            float v6 = (i + 6 < end) ? __uint_as_float(r6.y) : 0.f;
            float v7 = (i + 7 < end) ? __uint_as_float(r7.y) : 0.f;
            int   ca = g ? c4 : c0;  float va = g ? v4 : v0;
            int   cb = g ? c5 : c1;  float vb = g ? v5 : v1;
            int   cc = g ? c6 : c2;  float vc = g ? v6 : v2;
            int   cd = g ? c7 : c3;  float vd = g ? v7 : v3;
            a0 = fmaf(va, bf2f(tin[(size_t)ca * 32 + d]), a0);
            a1 = fmaf(vb, bf2f(tin[(size_t)cb * 32 + d]), a1);
            a2 = fmaf(vc, bf2f(tin[(size_t)cc * 32 + d]), a2);
            a3 = fmaf(vd, bf2f(tin[(size_t)cd * 32 + d]), a3);
        }
        acc = (a0 + a1) + (a2 + a3);
        acc += __shfl_xor(acc, 32);      // combine the two half-waves
    }

    // own ego value
    const int d = (DIN == 64) ? lane : (lane & 31);
    float e;
    if (EGO == 0) {
        e = (row < N_USERS) ? ue[(size_t)row * 64 + lane]
                            : ee[(size_t)(row - N_USERS) * 64 + lane];
    } else if (EGO == 1) {
        e = xin[(size_t)row * DIN + lane];
    } else {
        e = bf2f(tin[(size_t)row * DIN + d]);
    }
    float h = e + acc;
    float p = e * acc;
    if (DIN == 64 || lane < 32) {
        Hout[(size_t)row * DIN + d] = f2bf(h);
        Pout[(size_t)row * DIN + d] = f2bf(p);
    }
}

// ===========================================================================
// Pass 2: dense transform via MFMA. Block 256 = 4 waves, each wave owns 16
// rows; out = leaky(H@Wg+bg) + leaky(P@Wb+bb); writes bf16 tout (next gather
// table / scoring) [+ fp32 xout if WX] and the per-row L2 norm.
// mfma_f32_16x16x32_bf16 layouts: A[row=l&15][k=(l>>4)*8+j],
// B[k=(l>>4)*8+j][col=l&15], D col=l&15, row=(l>>4)*4+reg (m89-verified).
// ===========================================================================
template <int K, int NOUT, int WX>
__global__ __launch_bounds__(256) void transform_mfma(
        const unsigned short* __restrict__ H,
        const unsigned short* __restrict__ P,
        const unsigned short* __restrict__ WgT,   // bf16 [NOUT][K]
        const unsigned short* __restrict__ WbT,
        const float* __restrict__ bg, const float* __restrict__ bb,
        float* __restrict__ xout,                 // fp32 [N][NOUT] (if WX)
        unsigned short* __restrict__ tout,        // bf16 [N][NOUT]
        float* __restrict__ norm_out) {
    constexpr int NT = NOUT / 16;
    constexpr int KS = K / 32;
    const int lane    = threadIdx.x & 63;
    const int wave    = threadIdx.x >> 6;
    const int rowbase = blockIdx.x * 64 + wave * 16;
    const int r16 = lane & 15;
    const int g4  = lane >> 4;

    // A fragments (16 rows x K, bf16, contiguous 16 B per lane)
    bf16x8 ah[KS], ap[KS];
    const size_t arow = (size_t)(rowbase + r16) * K + g4 * 8;
#pragma unroll
    for (int s = 0; s < KS; ++s) {
        ah[s] = *reinterpret_cast<const bf16x8*>(H + arow + s * 32);
        ap[s] = *reinterpret_cast<const bf16x8*>(P + arow + s * 32);
    }

    f32x4 accg[NT], accb[NT];
#pragma unroll
    for (int t = 0; t < NT; ++t) {
        accg[t] = (f32x4){0.f, 0.f, 0.f, 0.f};
        accb[t] = (f32x4){0.f, 0.f, 0.f, 0.f};
    }
#pragma unroll
    for (int t = 0; t < NT; ++t) {
        const size_t brow = (size_t)(t * 16 + r16) * K + g4 * 8;
#pragma unroll
        for (int s = 0; s < KS; ++s) {
            bf16x8 bgf = *reinterpret_cast<const bf16x8*>(WgT + brow + s * 32);
            bf16x8 bbf = *reinterpret_cast<const bf16x8*>(WbT + brow + s * 32);
            accg[t] = __builtin_amdgcn_mfma_f32_16x16x32_bf16(ah[s], bgf, accg[t], 0, 0, 0);
            accb[t] = __builtin_amdgcn_mfma_f32_16x16x32_bf16(ap[s], bbf, accb[t], 0, 0, 0);
        }
    }

    // epilogue: bias + leaky + sum, stores, per-row norm
    float ss0 = 0.f, ss1 = 0.f, ss2 = 0.f, ss3 = 0.f;
#pragma unroll
    for (int t = 0; t < NT; ++t) {
        const int col = t * 16 + r16;
        const float bgv = bg[col];
        const float bbv = bb[col];
#pragma unroll
        for (int r = 0; r < 4; ++r) {
            float a = accg[t][r] + bgv; a = a > 0.f ? a : 0.01f * a;
            float b = accb[t][r] + bbv; b = b > 0.f ? b : 0.01f * b;
            float nv = a + b;
            const int row = rowbase + g4 * 4 + r;
            if (WX) xout[(size_t)row * NOUT + col] = nv;
            tout[(size_t)row * NOUT + col] = f2bf(nv);
            if (r == 0) ss0 += nv * nv;
            if (r == 1) ss1 += nv * nv;
            if (r == 2) ss2 += nv * nv;
            if (r == 3) ss3 += nv * nv;
        }
    }
#pragma unroll
    for (int off = 1; off < 16; off <<= 1) {
        ss0 += __shfl_xor(ss0, off);
        ss1 += __shfl_xor(ss1, off);
        ss2 += __shfl_xor(ss2, off);
        ss3 += __shfl_xor(ss3, off);
    }
    float sv = ss0;
    sv = (r16 == 1) ? ss1 : sv;
    sv = (r16 == 2) ? ss2 : sv;
    sv = (r16 == 3) ? ss3 : sv;
    if (r16 < 4) norm_out[rowbase + g4 * 4 + r16] = fmaxf(sqrtf(sv), 1e-12f);
}

// ===========================================================================
// Scoring: one wave per batch element; sections 64 raw + 64 (e1 fp32) +
// 32 (t2 bf16) + 16 (t3 bf16); normalization folded as 1/(norm products).
// ===========================================================================
__global__ __launch_bounds__(256) void score_kernel(
        const int* __restrict__ users, const int* __restrict__ pos,
        const int* __restrict__ neg,
        const float* __restrict__ ue, const float* __restrict__ ee,
        const float* __restrict__ e1, const float* __restrict__ n0,
        const unsigned short* __restrict__ t2, const float* __restrict__ n1,
        const unsigned short* __restrict__ t3, const float* __restrict__ n2,
        float* __restrict__ out) {
    int gid  = blockIdx.x * 256 + threadIdx.x;
    int idx  = gid >> 6;
    int lane = gid & 63;
    if (idx >= BATCH) return;
    int u  = users[idx];
    int pe = pos[idx];
    int ne = neg[idx];
    int pn = N_USERS + pe;
    int nn = N_USERS + ne;

    float s1p = 1.0f / (n0[u] * n0[pn]);
    float s1n = 1.0f / (n0[u] * n0[nn]);
    float s2p = 1.0f / (n1[u] * n1[pn]);
    float s2n = 1.0f / (n1[u] * n1[nn]);
    float s3p = 1.0f / (n2[u] * n2[pn]);
    float s3n = 1.0f / (n2[u] * n2[nn]);

    float ap = 0.f, an = 0.f;
    {
        float xu = ue[(size_t)u * 64 + lane];
        ap += xu * ee[(size_t)pe * 64 + lane];
        an += xu * ee[(size_t)ne * 64 + lane];
    }
    {
        float xu = e1[(size_t)u * 64 + lane];
        ap += xu * e1[(size_t)pn * 64 + lane] * s1p;
        an += xu * e1[(size_t)nn * 64 + lane] * s1n;
    }
    if (lane < 32) {
        float xu = bf2f(t2[(size_t)u * 32 + lane]);
        ap += xu * bf2f(t2[(size_t)pn * 32 + lane]) * s2p;
        an += xu * bf2f(t2[(size_t)nn * 32 + lane]) * s2n;
    } else if (lane < 48) {
        int d = lane - 32;
        float xu = bf2f(t3[(size_t)u * 16 + d]);
        ap += xu * bf2f(t3[(size_t)pn * 16 + d]) * s3p;
        an += xu * bf2f(t3[(size_t)nn * 16 + d]) * s3n;
    }
#pragma unroll
    for (int off = 32; off > 0; off >>= 1) {
        ap += __shfl_xor(ap, off);
        an += __shfl_xor(an, off);
    }
    if (lane == 0) {
        out[2 * idx + 0] = ap;
        out[2 * idx + 1] = an;
    }
}

// ===========================================================================
extern "C" void kernel_launch(void* const* d_in, const int* in_sizes, int n_in,
                              void* d_out, int out_size, void* d_ws, size_t ws_size,
                              hipStream_t stream) {
    const int*   users = (const int*)d_in[0];
    const int*   pos   = (const int*)d_in[1];
    const int*   neg   = (const int*)d_in[2];
    const int*   rows  = (const int*)d_in[3];
    const int*   cols  = (const int*)d_in[4];
    const float* vals  = (const float*)d_in[5];
    const float* ue    = (const float*)d_in[6];
    const float* ee    = (const float*)d_in[7];
    const float* Wg0 = (const float*)d_in[8],  *bg0 = (const float*)d_in[9];
    const float* Wb0 = (const float*)d_in[10], *bb0 = (const float*)d_in[11];
    const float* Wg1 = (const float*)d_in[12], *bg1 = (const float*)d_in[13];
    const float* Wb1 = (const float*)d_in[14], *bb1 = (const float*)d_in[15];
    const float* Wg2 = (const float*)d_in[16], *bg2 = (const float*)d_in[17];
    const float* Wb2 = (const float*)d_in[18], *bb2 = (const float*)d_in[19];

    // workspace (~181 MB; >=192 MB proven available)
    float* e1   = (float*)d_ws;                          // N x 64 fp32 (unnorm L1 out)
    float* n0   = e1 + (size_t)N_NODES * 64;             // N
    float* n1   = n0 + N_NODES;                          // N
    float* n2   = n1 + N_NODES;                          // N
    uint2* ep   = (uint2*)(n2 + N_NODES);                // E packed {col, val} (8 B)
    unsigned short* tA = (unsigned short*)(ep + NE);     // N x 64 bf16 (t0, then t2)
    unsigned short* tB = tA + (size_t)N_NODES * 64;      // N x 64 bf16 (t1)
    unsigned short* t3 = tB + (size_t)N_NODES * 64;      // N x 16 bf16 (L3 out)
    unsigned short* Hb = t3 + (size_t)N_NODES * 16;      // N x 64 bf16
    unsigned short* Pb = Hb + (size_t)N_NODES * 64;      // N x 64 bf16
    unsigned short* wt = Pb + (size_t)N_NODES * 64;      // 13312 (transposed weights)
    int* deg  = (int*)(wt + 13312);                      // N
    int* rs   = deg + N_NODES;                           // N
    int* blk  = rs + N_NODES;                            // 1024

    // ---- CSR build + bf16 layer-0 table + weight transpose (once) ----
    hipMemsetAsync(deg, 0, N_NODES * sizeof(int), stream);
    hist_kernel<<<(NE / 4 + 255) / 256, 256, 0, stream>>>((const int4*)rows, deg);
    scan1<<<NB, 256, 0, stream>>>(deg, rs, blk);
    scan2<<<1, 1024, 0, stream>>>(blk);
    scan3<<<NB, 256, 0, stream>>>(rs, blk);
    fill_kernel<<<(NE + 255) / 256, 256, 0, stream>>>(rows, cols, vals, rs, ep);
    build_t0<<<(N_NODES * 64 / 4 + 255) / 256, 256, 0, stream>>>(ue, ee, tA);
    prep_wt<<<(13312 + 255) / 256, 256, 0, stream>>>(Wg0, Wb0, Wg1, Wb1, Wg2, Wb2, wt);

    // ---- 3 layers: scalar-CSR gather pass + MFMA transform pass ----
    const int ggrid = N_NODES * 64 / 256;   // 50000, wave per row
    const int tgrid = N_NODES / 64;         // 3125, 16 rows per wave

    gather_hp<64, 0><<<ggrid, 256, 0, stream>>>(rs, deg, ep, tA,
                                                ue, ee, nullptr, Hb, Pb);
    transform_mfma<64, 64, 1><<<tgrid, 256, 0, stream>>>(Hb, Pb, wt, wt + 4096,
                                                         bg0, bb0, e1, tB, n0);
    gather_hp<64, 1><<<ggrid, 256, 0, stream>>>(rs, deg, ep, tB,
                                                ue, ee, e1, Hb, Pb);
    transform_mfma<64, 32, 0><<<tgrid, 256, 0, stream>>>(Hb, Pb, wt + 8192, wt + 10240,
                                                         bg1, bb1, nullptr, tA, n1);
    gather_hp<32, 2><<<ggrid, 256, 0, stream>>>(rs, deg, ep, tA,
                                                ue, ee, nullptr, Hb, Pb);
    transform_mfma<32, 16, 0><<<tgrid, 256, 0, stream>>>(Hb, Pb, wt + 12288, wt + 12800,
                                                         bg2, bb2, nullptr, t3, n2);

    // ---- scoring ----
    score_kernel<<<(BATCH * 64) / 256, 256, 0, stream>>>(users, pos, neg, ue, ee,
                                                         e1, n0, tA, n1, t3, n2,
                                                         (float*)d_out);
}

// Round 3
// 548.323 us; speedup vs baseline: 2.6085x; 1.2162x over previous
//
#include <hip/hip_runtime.h>

#define N_USERS 50000
#define N_ENT   150000
#define N_NODES 200000
#define NE      2000000
#define BATCH   8192

// bucket sort params: 512 rows per bucket
#define BSHIFT 9
#define BROWS  512
#define NBUK   391            // ceil(200000 / 512)
#define EPB    4096           // edges per block in hist/partition
#define PBLK   489            // ceil(NE / EPB)

typedef __attribute__((ext_vector_type(8))) short   bf16x8;
typedef __attribute__((ext_vector_type(4))) float   f32x4;

__device__ __forceinline__ float bf2f(unsigned short b) {
    return __uint_as_float(((unsigned int)b) << 16);
}
__device__ __forceinline__ unsigned short f2bf(float f) {
    unsigned int u = __float_as_uint(f);
    u += 0x7FFF + ((u >> 16) & 1);          // round-to-nearest-even
    return (unsigned short)(u >> 16);
}

// ===========================================================================
// CSR build via 2-level bucket sort (replaces hist + 3 scans + global-atomic
// fill whose random 8 B scatter cost 126 MB of 64 B-sector write amp):
//   bhist: LDS histogram of bucket (row>>9) counts
//   bscan: exclusive scan of 391 bucket counts (= CSR bucket bases)
//   part_kernel: partition edges bucket-contiguous (block-reserved runs)
//   bfill: one block per bucket; LDS row-hist + LDS scan -> rs/deg, then
//          LDS-cursor scatter into the bucket's ~40 KB CSR slice (L2-local)
// ===========================================================================
__global__ __launch_bounds__(256) void bhist(const int* __restrict__ rows,
                                             int* __restrict__ bcnt) {
    __shared__ int lcnt[NBUK];
    for (int b = threadIdx.x; b < NBUK; b += 256) lcnt[b] = 0;
    __syncthreads();
    const int e0 = blockIdx.x * EPB;
#pragma unroll
    for (int k = 0; k < EPB / 256; ++k) {
        int e = e0 + k * 256 + threadIdx.x;
        if (e < NE) atomicAdd(&lcnt[rows[e] >> BSHIFT], 1);
    }
    __syncthreads();
    for (int b = threadIdx.x; b < NBUK; b += 256) {
        int c = lcnt[b];
        if (c) atomicAdd(&bcnt[b], c);
    }
}

__global__ __launch_bounds__(512) void bscan(const int* __restrict__ bcnt,
                                             int* __restrict__ bsc,
                                             int* __restrict__ gcur) {
    __shared__ int buf[512];
    int t = threadIdx.x;
    int v = (t < NBUK) ? bcnt[t] : 0;
    buf[t] = v;
    __syncthreads();
    for (int off = 1; off < 512; off <<= 1) {
        int x = (t >= off) ? buf[t - off] : 0;
        __syncthreads();
        buf[t] += x;
        __syncthreads();
    }
    if (t < NBUK) {
        int excl = buf[t] - v;
        bsc[t]  = excl;
        gcur[t] = excl;
    }
    if (t == NBUK - 1) bsc[NBUK] = buf[t];   // == NE
}

// partition: records packed {(lrow<<18)|col, val_bits}; each block reserves
// one contiguous run per bucket -> coalesced-ish writes, no hot atomics.
__global__ __launch_bounds__(256) void part_kernel(const int* __restrict__ rows,
                                                   const int* __restrict__ cols,
                                                   const float* __restrict__ vals,
                                                   int* __restrict__ gcur,
                                                   uint2* __restrict__ part) {
    __shared__ int lcnt[NBUK];
    __shared__ int lbase[NBUK];
    for (int b = threadIdx.x; b < NBUK; b += 256) lcnt[b] = 0;
    __syncthreads();
    const int e0 = blockIdx.x * EPB;
    int rcache[EPB / 256];
#pragma unroll
    for (int k = 0; k < EPB / 256; ++k) {
        int e = e0 + k * 256 + threadIdx.x;
        int r = (e < NE) ? rows[e] : -1;
        rcache[k] = r;
        if (r >= 0) atomicAdd(&lcnt[r >> BSHIFT], 1);
    }
    __syncthreads();
    for (int b = threadIdx.x; b < NBUK; b += 256) {
        int c = lcnt[b];
        lbase[b] = c ? atomicAdd(&gcur[b], c) : 0;
        lcnt[b] = 0;                       // reset for rank assignment
    }
    __syncthreads();
#pragma unroll
    for (int k = 0; k < EPB / 256; ++k) {
        int e = e0 + k * 256 + threadIdx.x;
        int r = rcache[k];
        if (r >= 0) {
            int b    = r >> BSHIFT;
            int rank = atomicAdd(&lcnt[b], 1);
            uint2 rec;
            rec.x = ((unsigned)(r & (BROWS - 1)) << 18) | (unsigned)cols[e];
            rec.y = __float_as_uint(vals[e]);
            part[lbase[b] + rank] = rec;
        }
    }
}

// one block per bucket: row-hist -> LDS scan -> rs/deg, then LDS-cursor fill
__global__ __launch_bounds__(512) void bfill(const uint2* __restrict__ part,
                                             const int* __restrict__ bsc,
                                             int* __restrict__ rs,
                                             int* __restrict__ deg,
                                             uint2* __restrict__ ep) {
    __shared__ int h[BROWS];
    __shared__ int sc[BROWS];
    const int b = blockIdx.x;
    const int t = threadIdx.x;
    const int s = bsc[b];
    const int e = bsc[b + 1];
    h[t] = 0;
    __syncthreads();
    for (int i = s + t; i < e; i += 512)
        atomicAdd(&h[part[i].x >> 18], 1);
    __syncthreads();
    int v = h[t];
    sc[t] = v;
    __syncthreads();
    for (int off = 1; off < 512; off <<= 1) {
        int x = (t >= off) ? sc[t - off] : 0;
        __syncthreads();
        sc[t] += x;
        __syncthreads();
    }
    const int row = b * BROWS + t;
    if (row < N_NODES) {
        deg[row] = v;
        rs[row]  = s + sc[t];              // row_end (inclusive-scan) convention
    }
    h[t] = s + sc[t] - v;                  // cursor = row_start
    __syncthreads();
    for (int i = s + t; i < e; i += 512) {
        uint2 rec = part[i];
        int lr  = rec.x >> 18;
        int pos = atomicAdd(&h[lr], 1);
        uint2 o;
        o.x = rec.x & 0x3FFFF;
        o.y = rec.y;
        ep[pos] = o;                       // bucket slice ~40 KB -> L2-local
    }
}

// ---------------------------------------------------------------------------
// t0 = bf16(concat(ue, ee)) — the layer-0 gather table (one 128 B line/row).
// ---------------------------------------------------------------------------
__global__ __launch_bounds__(256) void build_t0(const float* __restrict__ ue,
                                                const float* __restrict__ ee,
                                                unsigned short* __restrict__ t0) {
    int i = blockIdx.x * 256 + threadIdx.x;              // float4 index
    const int total = N_NODES * 64 / 4;
    if (i >= total) return;
    const int uelems = N_USERS * 64 / 4;
    float4 v = (i < uelems) ? ((const float4*)ue)[i]
                            : ((const float4*)ee)[i - uelems];
    ushort4 o;
    o.x = f2bf(v.x); o.y = f2bf(v.y); o.z = f2bf(v.z); o.w = f2bf(v.w);
    ((ushort4*)t0)[i] = o;
}

// ---------------------------------------------------------------------------
// Pre-transpose weights to bf16 [n][k] (k contiguous) so MFMA B-fragments are
// contiguous 16 B loads. Layout in wt (ushort units): wg0T@0 wb0T@4096
// wg1T@8192 wb1T@10240 wg2T@12288 wb2T@12800 (total 13312)
// ---------------------------------------------------------------------------
__global__ __launch_bounds__(256) void prep_wt(
        const float* __restrict__ Wg0, const float* __restrict__ Wb0,
        const float* __restrict__ Wg1, const float* __restrict__ Wb1,
        const float* __restrict__ Wg2, const float* __restrict__ Wb2,
        unsigned short* __restrict__ wt) {
    int idx = blockIdx.x * 256 + threadIdx.x;
    if (idx < 4096) {                       // Wg0: 64x64
        int k = idx >> 6, n = idx & 63;
        wt[0 + n * 64 + k] = f2bf(Wg0[idx]);
    } else if (idx < 8192) {                // Wb0: 64x64
        int r = idx - 4096; int k = r >> 6, n = r & 63;
        wt[4096 + n * 64 + k] = f2bf(Wb0[r]);
    } else if (idx < 10240) {               // Wg1: 64x32
        int r = idx - 8192; int k = r >> 5, n = r & 31;
        wt[8192 + n * 64 + k] = f2bf(Wg1[r]);
    } else if (idx < 12288) {               // Wb1: 64x32
        int r = idx - 10240; int k = r >> 5, n = r & 31;
        wt[10240 + n * 64 + k] = f2bf(Wb1[r]);
    } else if (idx < 12800) {               // Wg2: 32x16
        int r = idx - 12288; int k = r >> 4, n = r & 15;
        wt[12288 + n * 32 + k] = f2bf(Wg2[r]);
    } else if (idx < 13312) {               // Wb2: 32x16
        int r = idx - 12800; int k = r >> 4, n = r & 15;
        wt[12800 + n * 32 + k] = f2bf(Wb2[r]);
    }
}

// ===========================================================================
// Pass 1: CSR gather, wave per row, ZERO LDS / ZERO shuffles on the hot path.
// row is forced to SGPR (readfirstlane) so rs/deg/ep become scalar (SMEM)
// loads; gathers are wave-coalesced 128 B line reads of the bf16 table.
// Emits H = e + side and P = e * side as bf16 (MFMA A-operands).
// EGO: 0 = ue/ee fp32 (layer0), 1 = xin fp32 (layer1), 2 = tin bf16 (layer2).
// Tail slots may read garbage records past row end -> UNSIGNED clamp of col,
// v forced to 0 so fma adds 0.
// ===========================================================================
template <int DIN, int EGO>
__global__ __launch_bounds__(256) void gather_hp(
        const int* __restrict__ rs, const int* __restrict__ deg,
        const uint2* __restrict__ ep,
        const unsigned short* __restrict__ tin,
        const float* __restrict__ ue, const float* __restrict__ ee,
        const float* __restrict__ xin,
        unsigned short* __restrict__ Hout,
        unsigned short* __restrict__ Pout) {
    const int lane  = threadIdx.x & 63;
    const int row_v = (blockIdx.x * 256 + threadIdx.x) >> 6;
    const int row   = __builtin_amdgcn_readfirstlane(row_v);
    const int end   = rs[row];
    const int start = end - deg[row];

    float acc;
    if (DIN == 64) {
        float a0 = 0.f, a1 = 0.f, a2 = 0.f, a3 = 0.f;
        for (int i = start; i < end; i += 4) {
            uint2 r0 = ep[i + 0];
            uint2 r1 = ep[i + 1];
            uint2 r2 = ep[i + 2];
            uint2 r3 = ep[i + 3];
            int c0 = (int)r0.x;
            int c1 = ((unsigned)r1.x < N_NODES) ? (int)r1.x : 0;
            int c2 = ((unsigned)r2.x < N_NODES) ? (int)r2.x : 0;
            int c3 = ((unsigned)r3.x < N_NODES) ? (int)r3.x : 0;
            float v0 = __uint_as_float(r0.y);
            float v1 = (i + 1 < end) ? __uint_as_float(r1.y) : 0.f;
            float v2 = (i + 2 < end) ? __uint_as_float(r2.y) : 0.f;
            float v3 = (i + 3 < end) ? __uint_as_float(r3.y) : 0.f;
            a0 = fmaf(v0, bf2f(tin[(size_t)c0 * 64 + lane]), a0);
            a1 = fmaf(v1, bf2f(tin[(size_t)c1 * 64 + lane]), a1);
            a2 = fmaf(v2, bf2f(tin[(size_t)c2 * 64 + lane]), a2);
            a3 = fmaf(v3, bf2f(tin[(size_t)c3 * 64 + lane]), a3);
        }
        acc = (a0 + a1) + (a2 + a3);
    } else {   // DIN == 32: two half-waves split the edge list (4 edges each)
        const int g = lane >> 5;
        const int d = lane & 31;
        float a0 = 0.f, a1 = 0.f, a2 = 0.f, a3 = 0.f;
        for (int i = start; i < end; i += 8) {
            uint2 r0 = ep[i + 0], r1 = ep[i + 1], r2 = ep[i + 2], r3 = ep[i + 3];
            uint2 r4 = ep[i + 4], r5 = ep[i + 5], r6 = ep[i + 6], r7 = ep[i + 7];
            int c0 = (int)r0.x;
            int c1 = ((unsigned)r1.x < N_NODES) ? (int)r1.x : 0;
            int c2 = ((unsigned)r2.x < N_NODES) ? (int)r2.x : 0;
            int c3 = ((unsigned)r3.x < N_NODES) ? (int)r3.x : 0;
            int c4 = ((unsigned)r4.x < N_NODES) ? (int)r4.x : 0;
            int c5 = ((unsigned)r5.x < N_NODES) ? (int)r5.x : 0;
            int c6 = ((unsigned)r6.x < N_NODES) ? (int)r6.x : 0;
            int c7 = ((unsigned)r7.x < N_NODES) ? (int)r7.x : 0;
            float v0 = __uint_as_float(r0.y);
            float v1 = (i + 1 < end) ? __uint_as_float(r1.y) : 0.f;
            float v2 = (i + 2 < end) ? __uint_as_float(r2.y) : 0.f;
            float v3 = (i + 3 < end) ? __uint_as_float(r3.y) : 0.f;
            float v4 = (i + 4 < end) ? __uint_as_float(r4.y) : 0.f;
            float v5 = (i + 5 < end) ? __uint_as_float(r5.y) : 0.f;
            float v6 = (i + 6 < end) ? __uint_as_float(r6.y) : 0.f;
            float v7 = (i + 7 < end) ? __uint_as_float(r7.y) : 0.f;
            int   ca = g ? c4 : c0;  float va = g ? v4 : v0;
            int   cb = g ? c5 : c1;  float vb = g ? v5 : v1;
            int   cc = g ? c6 : c2;  float vc = g ? v6 : v2;
            int   cd = g ? c7 : c3;  float vd = g ? v7 : v3;
            a0 = fmaf(va, bf2f(tin[(size_t)ca * 32 + d]), a0);
            a1 = fmaf(vb, bf2f(tin[(size_t)cb * 32 + d]), a1);
            a2 = fmaf(vc, bf2f(tin[(size_t)cc * 32 + d]), a2);
            a3 = fmaf(vd, bf2f(tin[(size_t)cd * 32 + d]), a3);
        }
        acc = (a0 + a1) + (a2 + a3);
        acc += __shfl_xor(acc, 32);      // combine the two half-waves
    }

    // own ego value
    const int d = (DIN == 64) ? lane : (lane & 31);
    float e;
    if (EGO == 0) {
        e = (row < N_USERS) ? ue[(size_t)row * 64 + lane]
                            : ee[(size_t)(row - N_USERS) * 64 + lane];
    } else if (EGO == 1) {
        e = xin[(size_t)row * DIN + lane];
    } else {
        e = bf2f(tin[(size_t)row * DIN + d]);
    }
    float h = e + acc;
    float p = e * acc;
    if (DIN == 64 || lane < 32) {
        Hout[(size_t)row * DIN + d] = f2bf(h);
        Pout[(size_t)row * DIN + d] = f2bf(p);
    }
}

// ===========================================================================
// Pass 2: dense transform via MFMA. Block 256 = 4 waves, each wave owns 16
// rows; out = leaky(H@Wg+bg) + leaky(P@Wb+bb); writes bf16 tout (next gather
// table / scoring) [+ fp32 xout if WX] and the per-row L2 norm.
// mfma_f32_16x16x32_bf16 layouts: A[row=l&15][k=(l>>4)*8+j],
// B[k=(l>>4)*8+j][col=l&15], D col=l&15, row=(l>>4)*4+reg (m89-verified).
// ===========================================================================
template <int K, int NOUT, int WX>
__global__ __launch_bounds__(256) void transform_mfma(
        const unsigned short* __restrict__ H,
        const unsigned short* __restrict__ P,
        const unsigned short* __restrict__ WgT,   // bf16 [NOUT][K]
        const unsigned short* __restrict__ WbT,
        const float* __restrict__ bg, const float* __restrict__ bb,
        float* __restrict__ xout,                 // fp32 [N][NOUT] (if WX)
        unsigned short* __restrict__ tout,        // bf16 [N][NOUT]
        float* __restrict__ norm_out) {
    constexpr int NT = NOUT / 16;
    constexpr int KS = K / 32;
    const int lane    = threadIdx.x & 63;
    const int wave    = threadIdx.x >> 6;
    const int rowbase = blockIdx.x * 64 + wave * 16;
    const int r16 = lane & 15;
    const int g4  = lane >> 4;

    // A fragments (16 rows x K, bf16, contiguous 16 B per lane)
    bf16x8 ah[KS], ap[KS];
    const size_t arow = (size_t)(rowbase + r16) * K + g4 * 8;
#pragma unroll
    for (int s = 0; s < KS; ++s) {
        ah[s] = *reinterpret_cast<const bf16x8*>(H + arow + s * 32);
        ap[s] = *reinterpret_cast<const bf16x8*>(P + arow + s * 32);
    }

    f32x4 accg[NT], accb[NT];
#pragma unroll
    for (int t = 0; t < NT; ++t) {
        accg[t] = (f32x4){0.f, 0.f, 0.f, 0.f};
        accb[t] = (f32x4){0.f, 0.f, 0.f, 0.f};
    }
#pragma unroll
    for (int t = 0; t < NT; ++t) {
        const size_t brow = (size_t)(t * 16 + r16) * K + g4 * 8;
#pragma unroll
        for (int s = 0; s < KS; ++s) {
            bf16x8 bgf = *reinterpret_cast<const bf16x8*>(WgT + brow + s * 32);
            bf16x8 bbf = *reinterpret_cast<const bf16x8*>(WbT + brow + s * 32);
            accg[t] = __builtin_amdgcn_mfma_f32_16x16x32_bf16(ah[s], bgf, accg[t], 0, 0, 0);
            accb[t] = __builtin_amdgcn_mfma_f32_16x16x32_bf16(ap[s], bbf, accb[t], 0, 0, 0);
        }
    }

    // epilogue: bias + leaky + sum, stores, per-row norm
    float ss0 = 0.f, ss1 = 0.f, ss2 = 0.f, ss3 = 0.f;
#pragma unroll
    for (int t = 0; t < NT; ++t) {
        const int col = t * 16 + r16;
        const float bgv = bg[col];
        const float bbv = bb[col];
#pragma unroll
        for (int r = 0; r < 4; ++r) {
            float a = accg[t][r] + bgv; a = a > 0.f ? a : 0.01f * a;
            float b = accb[t][r] + bbv; b = b > 0.f ? b : 0.01f * b;
            float nv = a + b;
            const int row = rowbase + g4 * 4 + r;
            if (WX) xout[(size_t)row * NOUT + col] = nv;
            tout[(size_t)row * NOUT + col] = f2bf(nv);
            if (r == 0) ss0 += nv * nv;
            if (r == 1) ss1 += nv * nv;
            if (r == 2) ss2 += nv * nv;
            if (r == 3) ss3 += nv * nv;
        }
    }
#pragma unroll
    for (int off = 1; off < 16; off <<= 1) {
        ss0 += __shfl_xor(ss0, off);
        ss1 += __shfl_xor(ss1, off);
        ss2 += __shfl_xor(ss2, off);
        ss3 += __shfl_xor(ss3, off);
    }
    float sv = ss0;
    sv = (r16 == 1) ? ss1 : sv;
    sv = (r16 == 2) ? ss2 : sv;
    sv = (r16 == 3) ? ss3 : sv;
    if (r16 < 4) norm_out[rowbase + g4 * 4 + r16] = fmaxf(sqrtf(sv), 1e-12f);
}

// ===========================================================================
// Scoring: one wave per batch element; sections 64 raw + 64 (e1 fp32) +
// 32 (t2 bf16) + 16 (t3 bf16); normalization folded as 1/(norm products).
// ===========================================================================
__global__ __launch_bounds__(256) void score_kernel(
        const int* __restrict__ users, const int* __restrict__ pos,
        const int* __restrict__ neg,
        const float* __restrict__ ue, const float* __restrict__ ee,
        const float* __restrict__ e1, const float* __restrict__ n0,
        const unsigned short* __restrict__ t2, const float* __restrict__ n1,
        const unsigned short* __restrict__ t3, const float* __restrict__ n2,
        float* __restrict__ out) {
    int gid  = blockIdx.x * 256 + threadIdx.x;
    int idx  = gid >> 6;
    int lane = gid & 63;
    if (idx >= BATCH) return;
    int u  = users[idx];
    int pe = pos[idx];
    int ne = neg[idx];
    int pn = N_USERS + pe;
    int nn = N_USERS + ne;

    float s1p = 1.0f / (n0[u] * n0[pn]);
    float s1n = 1.0f / (n0[u] * n0[nn]);
    float s2p = 1.0f / (n1[u] * n1[pn]);
    float s2n = 1.0f / (n1[u] * n1[nn]);
    float s3p = 1.0f / (n2[u] * n2[pn]);
    float s3n = 1.0f / (n2[u] * n2[nn]);

    float ap = 0.f, an = 0.f;
    {
        float xu = ue[(size_t)u * 64 + lane];
        ap += xu * ee[(size_t)pe * 64 + lane];
        an += xu * ee[(size_t)ne * 64 + lane];
    }
    {
        float xu = e1[(size_t)u * 64 + lane];
        ap += xu * e1[(size_t)pn * 64 + lane] * s1p;
        an += xu * e1[(size_t)nn * 64 + lane] * s1n;
    }
    if (lane < 32) {
        float xu = bf2f(t2[(size_t)u * 32 + lane]);
        ap += xu * bf2f(t2[(size_t)pn * 32 + lane]) * s2p;
        an += xu * bf2f(t2[(size_t)nn * 32 + lane]) * s2n;
    } else if (lane < 48) {
        int d = lane - 32;
        float xu = bf2f(t3[(size_t)u * 16 + d]);
        ap += xu * bf2f(t3[(size_t)pn * 16 + d]) * s3p;
        an += xu * bf2f(t3[(size_t)nn * 16 + d]) * s3n;
    }
#pragma unroll
    for (int off = 32; off > 0; off >>= 1) {
        ap += __shfl_xor(ap, off);
        an += __shfl_xor(an, off);
    }
    if (lane == 0) {
        out[2 * idx + 0] = ap;
        out[2 * idx + 1] = an;
    }
}

// ===========================================================================
extern "C" void kernel_launch(void* const* d_in, const int* in_sizes, int n_in,
                              void* d_out, int out_size, void* d_ws, size_t ws_size,
                              hipStream_t stream) {
    const int*   users = (const int*)d_in[0];
    const int*   pos   = (const int*)d_in[1];
    const int*   neg   = (const int*)d_in[2];
    const int*   rows  = (const int*)d_in[3];
    const int*   cols  = (const int*)d_in[4];
    const float* vals  = (const float*)d_in[5];
    const float* ue    = (const float*)d_in[6];
    const float* ee    = (const float*)d_in[7];
    const float* Wg0 = (const float*)d_in[8],  *bg0 = (const float*)d_in[9];
    const float* Wb0 = (const float*)d_in[10], *bb0 = (const float*)d_in[11];
    const float* Wg1 = (const float*)d_in[12], *bg1 = (const float*)d_in[13];
    const float* Wb1 = (const float*)d_in[14], *bb1 = (const float*)d_in[15];
    const float* Wg2 = (const float*)d_in[16], *bg2 = (const float*)d_in[17];
    const float* Wb2 = (const float*)d_in[18], *bb2 = (const float*)d_in[19];

    // workspace (~181 MB; >=192 MB proven available)
    float* e1   = (float*)d_ws;                          // N x 64 fp32 (unnorm L1 out)
    float* n0   = e1 + (size_t)N_NODES * 64;             // N
    float* n1   = n0 + N_NODES;                          // N
    float* n2   = n1 + N_NODES;                          // N
    uint2* ep   = (uint2*)(n2 + N_NODES);                // E packed {col, val} (8 B)
    unsigned short* tA = (unsigned short*)(ep + NE);     // N x 64 bf16 (t0, then t2)
    unsigned short* tB = tA + (size_t)N_NODES * 64;      // N x 64 bf16 (t1)
    unsigned short* t3 = tB + (size_t)N_NODES * 64;      // N x 16 bf16 (L3 out)
    unsigned short* Hb = t3 + (size_t)N_NODES * 16;      // N x 64 bf16
    unsigned short* Pb = Hb + (size_t)N_NODES * 64;      // N x 64 bf16
    unsigned short* wt = Pb + (size_t)N_NODES * 64;      // 13312 (transposed weights)
    int* deg  = (int*)(wt + 13312);                      // N
    int* rs   = deg + N_NODES;                           // N
    int* bcnt = rs + N_NODES;                            // NBUK
    int* bsc  = bcnt + NBUK;                             // NBUK + 1
    int* gcur = bsc + NBUK + 1;                          // NBUK
    uint2* part = (uint2*)e1;                            // E records (16 MB),
                                                         // reuses e1 (free until
                                                         // transform-0 writes it)

    // ---- CSR build via bucket sort + bf16 t0 table + weight transpose ----
    hipMemsetAsync(bcnt, 0, NBUK * sizeof(int), stream);
    bhist<<<PBLK, 256, 0, stream>>>(rows, bcnt);
    bscan<<<1, 512, 0, stream>>>(bcnt, bsc, gcur);
    part_kernel<<<PBLK, 256, 0, stream>>>(rows, cols, vals, gcur, part);
    bfill<<<NBUK, 512, 0, stream>>>(part, bsc, rs, deg, ep);
    build_t0<<<(N_NODES * 64 / 4 + 255) / 256, 256, 0, stream>>>(ue, ee, tA);
    prep_wt<<<(13312 + 255) / 256, 256, 0, stream>>>(Wg0, Wb0, Wg1, Wb1, Wg2, Wb2, wt);

    // ---- 3 layers: scalar-CSR gather pass + MFMA transform pass ----
    const int ggrid = N_NODES * 64 / 256;   // 50000, wave per row
    const int tgrid = N_NODES / 64;         // 3125, 16 rows per wave

    gather_hp<64, 0><<<ggrid, 256, 0, stream>>>(rs, deg, ep, tA,
                                                ue, ee, nullptr, Hb, Pb);
    transform_mfma<64, 64, 1><<<tgrid, 256, 0, stream>>>(Hb, Pb, wt, wt + 4096,
                                                         bg0, bb0, e1, tB, n0);
    gather_hp<64, 1><<<ggrid, 256, 0, stream>>>(rs, deg, ep, tB,
                                                ue, ee, e1, Hb, Pb);
    transform_mfma<64, 32, 0><<<tgrid, 256, 0, stream>>>(Hb, Pb, wt + 8192, wt + 10240,
                                                         bg1, bb1, nullptr, tA, n1);
    gather_hp<32, 2><<<ggrid, 256, 0, stream>>>(rs, deg, ep, tA,
                                                ue, ee, nullptr, Hb, Pb);
    transform_mfma<32, 16, 0><<<tgrid, 256, 0, stream>>>(Hb, Pb, wt + 12288, wt + 12800,
                                                         bg2, bb2, nullptr, t3, n2);

    // ---- scoring ----
    score_kernel<<<(BATCH * 64) / 256, 256, 0, stream>>>(users, pos, neg, ue, ee,
                                                         e1, n0, tA, n1, t3, n2,
                                                         (float*)d_out);
}

// Round 4
// 474.075 us; speedup vs baseline: 3.0171x; 1.1566x over previous
//
#include <hip/hip_runtime.h>

#define N_USERS 50000
#define N_ENT   150000
#define N_NODES 200000
#define NE      2000000
#define BATCH   8192

// bucket sort params: 512 rows per bucket
#define BSHIFT 9
#define BROWS  512
#define NBUK   391            // ceil(200000 / 512)
#define EPB    4096           // edges per block in hist/partition
#define PBLK   489            // ceil(NE / EPB)
#define T0_BLKS 12500         // N_NODES*64/4 / 256
#define WT_BLKS 52            // ceil(13312 / 256)

typedef __attribute__((ext_vector_type(8))) short   bf16x8;
typedef __attribute__((ext_vector_type(4))) float   f32x4;

__device__ __forceinline__ float bf2f(unsigned short b) {
    return __uint_as_float(((unsigned int)b) << 16);
}
__device__ __forceinline__ unsigned short f2bf(float f) {
    unsigned int u = __float_as_uint(f);
    u += 0x7FFF + ((u >> 16) & 1);          // round-to-nearest-even
    return (unsigned short)(u >> 16);
}

// ===========================================================================
// CSR build via 2-level bucket sort:
//   bhist: LDS histogram of bucket (row>>9) counts       (int4 streamed)
//   bscan: exclusive scan of 391 bucket counts
//   part_kernel: partition edges bucket-contiguous       (int4/float4 streamed)
//   bfill: per-bucket LDS row-hist + scan -> rs/deg, LDS-cursor CSR fill
// ===========================================================================
__global__ __launch_bounds__(256) void bhist(const int4* __restrict__ rows4,
                                             int* __restrict__ bcnt) {
    __shared__ int lcnt[NBUK];
    for (int b = threadIdx.x; b < NBUK; b += 256) lcnt[b] = 0;
    __syncthreads();
    const int q0 = blockIdx.x * (EPB / 4);
#pragma unroll
    for (int k = 0; k < 4; ++k) {
        int q = q0 + k * 256 + threadIdx.x;
        if (q < NE / 4) {
            int4 r = rows4[q];
            atomicAdd(&lcnt[r.x >> BSHIFT], 1);
            atomicAdd(&lcnt[r.y >> BSHIFT], 1);
            atomicAdd(&lcnt[r.z >> BSHIFT], 1);
            atomicAdd(&lcnt[r.w >> BSHIFT], 1);
        }
    }
    __syncthreads();
    for (int b = threadIdx.x; b < NBUK; b += 256) {
        int c = lcnt[b];
        if (c) atomicAdd(&bcnt[b], c);
    }
}

__global__ __launch_bounds__(512) void bscan(const int* __restrict__ bcnt,
                                             int* __restrict__ bsc,
                                             int* __restrict__ gcur) {
    __shared__ int buf[512];
    int t = threadIdx.x;
    int v = (t < NBUK) ? bcnt[t] : 0;
    buf[t] = v;
    __syncthreads();
    for (int off = 1; off < 512; off <<= 1) {
        int x = (t >= off) ? buf[t - off] : 0;
        __syncthreads();
        buf[t] += x;
        __syncthreads();
    }
    if (t < NBUK) {
        int excl = buf[t] - v;
        bsc[t]  = excl;
        gcur[t] = excl;
    }
    if (t == NBUK - 1) bsc[NBUK] = buf[t];   // == NE
}

// partition: records packed {(lrow<<18)|col, val_bits}; each block reserves
// one contiguous run per bucket -> coalesced-ish writes, no hot atomics.
__global__ __launch_bounds__(256) void part_kernel(const int4* __restrict__ rows4,
                                                   const int4* __restrict__ cols4,
                                                   const float4* __restrict__ vals4,
                                                   int* __restrict__ gcur,
                                                   uint2* __restrict__ part) {
    __shared__ int lcnt[NBUK];
    __shared__ int lbase[NBUK];
    for (int b = threadIdx.x; b < NBUK; b += 256) lcnt[b] = 0;
    __syncthreads();
    const int q0 = blockIdx.x * (EPB / 4);
    int4 rc[4];
#pragma unroll
    for (int k = 0; k < 4; ++k) {
        int q = q0 + k * 256 + threadIdx.x;
        if (q < NE / 4) {
            int4 r = rows4[q];
            rc[k] = r;
            atomicAdd(&lcnt[r.x >> BSHIFT], 1);
            atomicAdd(&lcnt[r.y >> BSHIFT], 1);
            atomicAdd(&lcnt[r.z >> BSHIFT], 1);
            atomicAdd(&lcnt[r.w >> BSHIFT], 1);
        } else {
            rc[k] = make_int4(-1, -1, -1, -1);
        }
    }
    __syncthreads();
    for (int b = threadIdx.x; b < NBUK; b += 256) {
        int c = lcnt[b];
        lbase[b] = c ? atomicAdd(&gcur[b], c) : 0;
        lcnt[b] = 0;                       // reset for rank assignment
    }
    __syncthreads();
#pragma unroll
    for (int k = 0; k < 4; ++k) {
        int q = q0 + k * 256 + threadIdx.x;
        if (q < NE / 4) {
            int4   c4 = cols4[q];
            float4 v4 = vals4[q];
            int r, b, rk;
            uint2 rec;
            r = rc[k].x; b = r >> BSHIFT; rk = atomicAdd(&lcnt[b], 1);
            rec.x = ((unsigned)(r & (BROWS - 1)) << 18) | (unsigned)c4.x;
            rec.y = __float_as_uint(v4.x);  part[lbase[b] + rk] = rec;
            r = rc[k].y; b = r >> BSHIFT; rk = atomicAdd(&lcnt[b], 1);
            rec.x = ((unsigned)(r & (BROWS - 1)) << 18) | (unsigned)c4.y;
            rec.y = __float_as_uint(v4.y);  part[lbase[b] + rk] = rec;
            r = rc[k].z; b = r >> BSHIFT; rk = atomicAdd(&lcnt[b], 1);
            rec.x = ((unsigned)(r & (BROWS - 1)) << 18) | (unsigned)c4.z;
            rec.y = __float_as_uint(v4.z);  part[lbase[b] + rk] = rec;
            r = rc[k].w; b = r >> BSHIFT; rk = atomicAdd(&lcnt[b], 1);
            rec.x = ((unsigned)(r & (BROWS - 1)) << 18) | (unsigned)c4.w;
            rec.y = __float_as_uint(v4.w);  part[lbase[b] + rk] = rec;
        }
    }
}

// one block per bucket: row-hist -> LDS scan -> rs/deg, then LDS-cursor fill
__global__ __launch_bounds__(512) void bfill(const uint2* __restrict__ part,
                                             const int* __restrict__ bsc,
                                             int* __restrict__ rs,
                                             int* __restrict__ deg,
                                             uint2* __restrict__ ep) {
    __shared__ int h[BROWS];
    __shared__ int sc[BROWS];
    const int b = blockIdx.x;
    const int t = threadIdx.x;
    const int s = bsc[b];
    const int e = bsc[b + 1];
    h[t] = 0;
    __syncthreads();
    for (int i = s + t; i < e; i += 512)
        atomicAdd(&h[part[i].x >> 18], 1);
    __syncthreads();
    int v = h[t];
    sc[t] = v;
    __syncthreads();
    for (int off = 1; off < 512; off <<= 1) {
        int x = (t >= off) ? sc[t - off] : 0;
        __syncthreads();
        sc[t] += x;
        __syncthreads();
    }
    const int row = b * BROWS + t;
    if (row < N_NODES) {
        deg[row] = v;
        rs[row]  = s + sc[t];              // row_end convention
    }
    h[t] = s + sc[t] - v;                  // cursor = row_start
    __syncthreads();
    for (int i = s + t; i < e; i += 512) {
        uint2 rec = part[i];
        int lr  = rec.x >> 18;
        int pos = atomicAdd(&h[lr], 1);
        uint2 o;
        o.x = rec.x & 0x3FFFF;
        o.y = rec.y;
        ep[pos] = o;                       // bucket slice ~40 KB -> L2-local
    }
}

// ---------------------------------------------------------------------------
// init_misc = build_t0 (blocks 0..12499) + weight transpose (blocks 12500+).
// t0 = bf16(concat(ue,ee)); wt layout (ushort): wg0T@0 wb0T@4096 wg1T@8192
// wb1T@10240 wg2T@12288 wb2T@12800 (total 13312), all [n][k] k-contiguous.
// ---------------------------------------------------------------------------
__global__ __launch_bounds__(256) void init_misc(
        const float* __restrict__ ue, const float* __restrict__ ee,
        unsigned short* __restrict__ t0,
        const float* __restrict__ Wg0, const float* __restrict__ Wb0,
        const float* __restrict__ Wg1, const float* __restrict__ Wb1,
        const float* __restrict__ Wg2, const float* __restrict__ Wb2,
        unsigned short* __restrict__ wt) {
    if (blockIdx.x < T0_BLKS) {
        int i = blockIdx.x * 256 + threadIdx.x;          // float4 index
        const int uelems = N_USERS * 64 / 4;
        float4 v = (i < uelems) ? ((const float4*)ue)[i]
                                : ((const float4*)ee)[i - uelems];
        ushort4 o;
        o.x = f2bf(v.x); o.y = f2bf(v.y); o.z = f2bf(v.z); o.w = f2bf(v.w);
        ((ushort4*)t0)[i] = o;
        return;
    }
    int idx = (blockIdx.x - T0_BLKS) * 256 + threadIdx.x;
    if (idx < 4096) {                       // Wg0: 64x64
        int k = idx >> 6, n = idx & 63;
        wt[0 + n * 64 + k] = f2bf(Wg0[idx]);
    } else if (idx < 8192) {                // Wb0: 64x64
        int r = idx - 4096; int k = r >> 6, n = r & 63;
        wt[4096 + n * 64 + k] = f2bf(Wb0[r]);
    } else if (idx < 10240) {               // Wg1: 64x32
        int r = idx - 8192; int k = r >> 5, n = r & 31;
        wt[8192 + n * 64 + k] = f2bf(Wg1[r]);
    } else if (idx < 12288) {               // Wb1: 64x32
        int r = idx - 10240; int k = r >> 5, n = r & 31;
        wt[10240 + n * 64 + k] = f2bf(Wb1[r]);
    } else if (idx < 12800) {               // Wg2: 32x16
        int r = idx - 12288; int k = r >> 4, n = r & 15;
        wt[12288 + n * 32 + k] = f2bf(Wg2[r]);
    } else if (idx < 13312) {               // Wb2: 32x16
        int r = idx - 12800; int k = r >> 4, n = r & 15;
        wt[12800 + n * 32 + k] = f2bf(Wb2[r]);
    }
}

// ===========================================================================
// Fused layer: gather (wave-per-row, scalar CSR, zero-shuffle) -> LDS H/P
// tile -> MFMA transform -> epilogue (leaky+sum, stores, norm via LDS
// partials). Eliminates the H/P HBM round trip (~100 MB/layer) and 3 dispatches.
// Block = 256 (4 waves), R rows/block with R*DOUT == 1024:
//   DOUT=64: R=16 (4 rows/wave), DOUT=32: R=32, DOUT=16: R=64.
// MFMA wave tasks: wave w -> rowTile w/NTC, colTile w%NTC (NTC = DOUT/16).
// mfma_f32_16x16x32_bf16: A[row=l&15][k=(l>>4)*8+j], B[k][col=l&15],
// D col=l&15, row=(l>>4)*4+reg  (layout verified in rounds 1-3).
// EGO: 0 = ue/ee fp32 (L0), 1 = xin fp32 (L1), 2 = tin bf16 (L2).
// ===========================================================================
template <int DIN, int DOUT, int EGO, int WX>
__global__ __launch_bounds__(256) void layer_fused(
        const int* __restrict__ rs, const int* __restrict__ deg,
        const uint2* __restrict__ ep,
        const unsigned short* __restrict__ tin,
        const float* __restrict__ ue, const float* __restrict__ ee,
        const float* __restrict__ xin,
        const unsigned short* __restrict__ WgT,   // bf16 [DOUT][DIN]
        const unsigned short* __restrict__ WbT,
        const float* __restrict__ bg, const float* __restrict__ bb,
        float* __restrict__ xout,                 // fp32 [N][DOUT] (if WX)
        unsigned short* __restrict__ tout,        // bf16 [N][DOUT]
        float* __restrict__ norm_out) {
    constexpr int NTC = DOUT / 16;        // col tiles per block
    constexpr int R   = (4 / NTC) * 16;   // rows per block
    constexpr int RPW = R / 4;            // rows gathered per wave
    constexpr int KS  = DIN / 32;

    __shared__ unsigned short sH[R * DIN];
    __shared__ unsigned short sP[R * DIN];
    __shared__ float sPart[R * NTC];

    const int lane    = threadIdx.x & 63;
    const int wave    = threadIdx.x >> 6;
    const int rowbase = blockIdx.x * R;

    // ---- gather phase: wave gathers its RPW rows sequentially ----
    for (int rr = 0; rr < RPW; ++rr) {
        const int lr  = wave * RPW + rr;
        const int row = __builtin_amdgcn_readfirstlane(rowbase + lr);
        const int end   = rs[row];
        const int start = end - deg[row];

        float acc;
        if (DIN == 64) {
            float a0 = 0.f, a1 = 0.f, a2 = 0.f, a3 = 0.f;
            for (int i = start; i < end; i += 4) {
                uint2 r0 = ep[i + 0], r1 = ep[i + 1];
                uint2 r2 = ep[i + 2], r3 = ep[i + 3];
                int c0 = (int)r0.x;
                int c1 = ((unsigned)r1.x < N_NODES) ? (int)r1.x : 0;
                int c2 = ((unsigned)r2.x < N_NODES) ? (int)r2.x : 0;
                int c3 = ((unsigned)r3.x < N_NODES) ? (int)r3.x : 0;
                float v0 = __uint_as_float(r0.y);
                float v1 = (i + 1 < end) ? __uint_as_float(r1.y) : 0.f;
                float v2 = (i + 2 < end) ? __uint_as_float(r2.y) : 0.f;
                float v3 = (i + 3 < end) ? __uint_as_float(r3.y) : 0.f;
                a0 = fmaf(v0, bf2f(tin[(size_t)c0 * 64 + lane]), a0);
                a1 = fmaf(v1, bf2f(tin[(size_t)c1 * 64 + lane]), a1);
                a2 = fmaf(v2, bf2f(tin[(size_t)c2 * 64 + lane]), a2);
                a3 = fmaf(v3, bf2f(tin[(size_t)c3 * 64 + lane]), a3);
            }
            acc = (a0 + a1) + (a2 + a3);
        } else {   // DIN == 32: two half-waves split the edge list
            const int g = lane >> 5;
            const int d = lane & 31;
            float a0 = 0.f, a1 = 0.f, a2 = 0.f, a3 = 0.f;
            for (int i = start; i < end; i += 8) {
                uint2 r0 = ep[i + 0], r1 = ep[i + 1], r2 = ep[i + 2], r3 = ep[i + 3];
                uint2 r4 = ep[i + 4], r5 = ep[i + 5], r6 = ep[i + 6], r7 = ep[i + 7];
                int c0 = (int)r0.x;
                int c1 = ((unsigned)r1.x < N_NODES) ? (int)r1.x : 0;
                int c2 = ((unsigned)r2.x < N_NODES) ? (int)r2.x : 0;
                int c3 = ((unsigned)r3.x < N_NODES) ? (int)r3.x : 0;
                int c4 = ((unsigned)r4.x < N_NODES) ? (int)r4.x : 0;
                int c5 = ((unsigned)r5.x < N_NODES) ? (int)r5.x : 0;
                int c6 = ((unsigned)r6.x < N_NODES) ? (int)r6.x : 0;
                int c7 = ((unsigned)r7.x < N_NODES) ? (int)r7.x : 0;
                float v0 = __uint_as_float(r0.y);
                float v1 = (i + 1 < end) ? __uint_as_float(r1.y) : 0.f;
                float v2 = (i + 2 < end) ? __uint_as_float(r2.y) : 0.f;
                float v3 = (i + 3 < end) ? __uint_as_float(r3.y) : 0.f;
                float v4 = (i + 4 < end) ? __uint_as_float(r4.y) : 0.f;
                float v5 = (i + 5 < end) ? __uint_as_float(r5.y) : 0.f;
                float v6 = (i + 6 < end) ? __uint_as_float(r6.y) : 0.f;
                float v7 = (i + 7 < end) ? __uint_as_float(r7.y) : 0.f;
                int   ca = g ? c4 : c0;  float va = g ? v4 : v0;
                int   cb = g ? c5 : c1;  float vb = g ? v5 : v1;
                int   cc = g ? c6 : c2;  float vc = g ? v6 : v2;
                int   cd = g ? c7 : c3;  float vd = g ? v7 : v3;
                a0 = fmaf(va, bf2f(tin[(size_t)ca * 32 + d]), a0);
                a1 = fmaf(vb, bf2f(tin[(size_t)cb * 32 + d]), a1);
                a2 = fmaf(vc, bf2f(tin[(size_t)cc * 32 + d]), a2);
                a3 = fmaf(vd, bf2f(tin[(size_t)cd * 32 + d]), a3);
            }
            acc = (a0 + a1) + (a2 + a3);
            acc += __shfl_xor(acc, 32);
        }

        // own ego value
        const int d = (DIN == 64) ? lane : (lane & 31);
        float e;
        if (EGO == 0) {
            e = (row < N_USERS) ? ue[(size_t)row * 64 + lane]
                                : ee[(size_t)(row - N_USERS) * 64 + lane];
        } else if (EGO == 1) {
            e = xin[(size_t)row * DIN + lane];
        } else {
            e = bf2f(tin[(size_t)row * DIN + d]);
        }
        float h = e + acc;
        float p = e * acc;
        if (DIN == 64 || lane < 32) {
            sH[lr * DIN + d] = f2bf(h);
            sP[lr * DIN + d] = f2bf(p);
        }
    }
    __syncthreads();

    // ---- MFMA phase: wave (rt, ct) computes 16 rows x 16 cols ----
    const int ct  = wave % NTC;
    const int rt  = wave / NTC;
    const int r16 = lane & 15;
    const int g4  = lane >> 4;

    bf16x8 ah[KS], ap[KS];
#pragma unroll
    for (int s = 0; s < KS; ++s) {
        const int aoff = (rt * 16 + r16) * DIN + g4 * 8 + s * 32;
        ah[s] = *reinterpret_cast<const bf16x8*>(sH + aoff);
        ap[s] = *reinterpret_cast<const bf16x8*>(sP + aoff);
    }
    f32x4 accg = (f32x4){0.f, 0.f, 0.f, 0.f};
    f32x4 accb = (f32x4){0.f, 0.f, 0.f, 0.f};
#pragma unroll
    for (int s = 0; s < KS; ++s) {
        const int boff = (ct * 16 + r16) * DIN + g4 * 8 + s * 32;
        bf16x8 bgf = *reinterpret_cast<const bf16x8*>(WgT + boff);
        bf16x8 bbf = *reinterpret_cast<const bf16x8*>(WbT + boff);
        accg = __builtin_amdgcn_mfma_f32_16x16x32_bf16(ah[s], bgf, accg, 0, 0, 0);
        accb = __builtin_amdgcn_mfma_f32_16x16x32_bf16(ap[s], bbf, accb, 0, 0, 0);
    }

    // epilogue: bias + leaky + sum, stores, per-row norm partials
    const int col = ct * 16 + r16;
    const float bgv = bg[col];
    const float bbv = bb[col];
    float ss[4];
#pragma unroll
    for (int r = 0; r < 4; ++r) {
        float a = accg[r] + bgv; a = a > 0.f ? a : 0.01f * a;
        float b = accb[r] + bbv; b = b > 0.f ? b : 0.01f * b;
        float nv = a + b;
        const int row = rowbase + rt * 16 + g4 * 4 + r;
        if (WX) xout[(size_t)row * DOUT + col] = nv;
        tout[(size_t)row * DOUT + col] = f2bf(nv);
        ss[r] = nv * nv;
    }
#pragma unroll
    for (int off = 1; off < 16; off <<= 1) {
#pragma unroll
        for (int r = 0; r < 4; ++r) ss[r] += __shfl_xor(ss[r], off);
    }
    if (r16 == 0) {
#pragma unroll
        for (int r = 0; r < 4; ++r)
            sPart[(rt * 16 + g4 * 4 + r) * NTC + ct] = ss[r];
    }
    __syncthreads();
    for (int t = threadIdx.x; t < R; t += 256) {
        float s = 0.f;
#pragma unroll
        for (int j = 0; j < NTC; ++j) s += sPart[t * NTC + j];
        norm_out[rowbase + t] = fmaxf(sqrtf(s), 1e-12f);
    }
}

// ===========================================================================
// Scoring: one wave per batch element; sections 64 raw + 64 (e1 fp32) +
// 32 (t2 bf16) + 16 (t3 bf16); normalization folded as 1/(norm products).
// ===========================================================================
__global__ __launch_bounds__(256) void score_kernel(
        const int* __restrict__ users, const int* __restrict__ pos,
        const int* __restrict__ neg,
        const float* __restrict__ ue, const float* __restrict__ ee,
        const float* __restrict__ e1, const float* __restrict__ n0,
        const unsigned short* __restrict__ t2, const float* __restrict__ n1,
        const unsigned short* __restrict__ t3, const float* __restrict__ n2,
        float* __restrict__ out) {
    int gid  = blockIdx.x * 256 + threadIdx.x;
    int idx  = gid >> 6;
    int lane = gid & 63;
    if (idx >= BATCH) return;
    int u  = users[idx];
    int pe = pos[idx];
    int ne = neg[idx];
    int pn = N_USERS + pe;
    int nn = N_USERS + ne;

    float s1p = 1.0f / (n0[u] * n0[pn]);
    float s1n = 1.0f / (n0[u] * n0[nn]);
    float s2p = 1.0f / (n1[u] * n1[pn]);
    float s2n = 1.0f / (n1[u] * n1[nn]);
    float s3p = 1.0f / (n2[u] * n2[pn]);
    float s3n = 1.0f / (n2[u] * n2[nn]);

    float ap = 0.f, an = 0.f;
    {
        float xu = ue[(size_t)u * 64 + lane];
        ap += xu * ee[(size_t)pe * 64 + lane];
        an += xu * ee[(size_t)ne * 64 + lane];
    }
    {
        float xu = e1[(size_t)u * 64 + lane];
        ap += xu * e1[(size_t)pn * 64 + lane] * s1p;
        an += xu * e1[(size_t)nn * 64 + lane] * s1n;
    }
    if (lane < 32) {
        float xu = bf2f(t2[(size_t)u * 32 + lane]);
        ap += xu * bf2f(t2[(size_t)pn * 32 + lane]) * s2p;
        an += xu * bf2f(t2[(size_t)nn * 32 + lane]) * s2n;
    } else if (lane < 48) {
        int d = lane - 32;
        float xu = bf2f(t3[(size_t)u * 16 + d]);
        ap += xu * bf2f(t3[(size_t)pn * 16 + d]) * s3p;
        an += xu * bf2f(t3[(size_t)nn * 16 + d]) * s3n;
    }
#pragma unroll
    for (int off = 32; off > 0; off >>= 1) {
        ap += __shfl_xor(ap, off);
        an += __shfl_xor(an, off);
    }
    if (lane == 0) {
        out[2 * idx + 0] = ap;
        out[2 * idx + 1] = an;
    }
}

// ===========================================================================
extern "C" void kernel_launch(void* const* d_in, const int* in_sizes, int n_in,
                              void* d_out, int out_size, void* d_ws, size_t ws_size,
                              hipStream_t stream) {
    const int*   users = (const int*)d_in[0];
    const int*   pos   = (const int*)d_in[1];
    const int*   neg   = (const int*)d_in[2];
    const int*   rows  = (const int*)d_in[3];
    const int*   cols  = (const int*)d_in[4];
    const float* vals  = (const float*)d_in[5];
    const float* ue    = (const float*)d_in[6];
    const float* ee    = (const float*)d_in[7];
    const float* Wg0 = (const float*)d_in[8],  *bg0 = (const float*)d_in[9];
    const float* Wb0 = (const float*)d_in[10], *bb0 = (const float*)d_in[11];
    const float* Wg1 = (const float*)d_in[12], *bg1 = (const float*)d_in[13];
    const float* Wb1 = (const float*)d_in[14], *bb1 = (const float*)d_in[15];
    const float* Wg2 = (const float*)d_in[16], *bg2 = (const float*)d_in[17];
    const float* Wb2 = (const float*)d_in[18], *bb2 = (const float*)d_in[19];

    // workspace (~128 MB; >=192 MB proven available)
    float* e1   = (float*)d_ws;                          // N x 64 fp32 (unnorm L1 out)
    float* n0   = e1 + (size_t)N_NODES * 64;             // N
    float* n1   = n0 + N_NODES;                          // N
    float* n2   = n1 + N_NODES;                          // N
    uint2* ep   = (uint2*)(n2 + N_NODES);                // E packed {col, val}
    unsigned short* tA = (unsigned short*)(ep + NE);     // N x 64 bf16 (t0, then t2)
    unsigned short* tB = tA + (size_t)N_NODES * 64;      // N x 64 bf16 (t1)
    unsigned short* t3 = tB + (size_t)N_NODES * 64;      // N x 16 bf16 (L3 out)
    unsigned short* wt = t3 + (size_t)N_NODES * 16;      // 13312 (transposed weights)
    int* deg  = (int*)(wt + 13312);                      // N
    int* rs   = deg + N_NODES;                           // N
    int* bcnt = rs + N_NODES;                            // NBUK
    int* bsc  = bcnt + NBUK;                             // NBUK + 1
    int* gcur = bsc + NBUK + 1;                          // NBUK
    uint2* part = (uint2*)e1;                            // E records (16 MB),
                                                         // reuses e1 (free until
                                                         // layer 0 writes it)

    // ---- CSR build via bucket sort + t0 table + weight transpose ----
    hipMemsetAsync(bcnt, 0, NBUK * sizeof(int), stream);
    bhist<<<PBLK, 256, 0, stream>>>((const int4*)rows, bcnt);
    bscan<<<1, 512, 0, stream>>>(bcnt, bsc, gcur);
    part_kernel<<<PBLK, 256, 0, stream>>>((const int4*)rows, (const int4*)cols,
                                          (const float4*)vals, gcur, part);
    bfill<<<NBUK, 512, 0, stream>>>(part, bsc, rs, deg, ep);
    init_misc<<<T0_BLKS + WT_BLKS, 256, 0, stream>>>(ue, ee, tA,
                                                     Wg0, Wb0, Wg1, Wb1, Wg2, Wb2, wt);

    // ---- 3 fused layers: gather -> LDS -> MFMA -> stores + norm ----
    layer_fused<64, 64, 0, 1><<<N_NODES / 16, 256, 0, stream>>>(
        rs, deg, ep, tA, ue, ee, nullptr, wt, wt + 4096, bg0, bb0, e1, tB, n0);
    layer_fused<64, 32, 1, 0><<<N_NODES / 32, 256, 0, stream>>>(
        rs, deg, ep, tB, ue, ee, e1, wt + 8192, wt + 10240, bg1, bb1, nullptr, tA, n1);
    layer_fused<32, 16, 2, 0><<<N_NODES / 64, 256, 0, stream>>>(
        rs, deg, ep, tA, ue, ee, nullptr, wt + 12288, wt + 12800, bg2, bb2, nullptr, t3, n2);

    // ---- scoring ----
    score_kernel<<<(BATCH * 64) / 256, 256, 0, stream>>>(users, pos, neg, ue, ee,
                                                         e1, n0, tA, n1, t3, n2,
                                                         (float*)d_out);
}

// Round 5
// 442.132 us; speedup vs baseline: 3.2351x; 1.0722x over previous
//
#include <hip/hip_runtime.h>

#define N_USERS 50000
#define N_ENT   150000
#define N_NODES 200000
#define NE      2000000
#define BATCH   8192

// bucket sort params: 512 rows per bucket
#define BSHIFT 9
#define BROWS  512
#define NBUK   391            // ceil(200000 / 512)
#define EPB    8192           // edges per block in hist/partition
#define PBLK   245            // ceil(NE / EPB)
#define T0_BLKS 12500         // N_NODES*64/4 / 256
#define WT_BLKS 52            // ceil(13312 / 256)

typedef __attribute__((ext_vector_type(8))) short   bf16x8;
typedef __attribute__((ext_vector_type(4))) float   f32x4;
typedef unsigned int u32;

__device__ __forceinline__ float bf2f(unsigned short b) {
    return __uint_as_float(((u32)b) << 16);
}
__device__ __forceinline__ float bflo(u32 x) {          // low bf16 of a pair
    return __uint_as_float(x << 16);
}
__device__ __forceinline__ float bfhi(u32 x) {          // high bf16 of a pair
    return __uint_as_float(x & 0xFFFF0000u);
}
__device__ __forceinline__ unsigned short f2bf(float f) {
    u32 u = __float_as_uint(f);
    u += 0x7FFF + ((u >> 16) & 1);          // round-to-nearest-even
    return (unsigned short)(u >> 16);
}

// ===========================================================================
// CSR build via 2-level bucket sort:
//   bhist: LDS histogram of bucket (row>>9) counts       (int4 streamed)
//   bscan: exclusive scan of 391 bucket counts
//   part_kernel: partition edges bucket-contiguous       (int4/float4 streamed)
//   bfill: per-bucket LDS row-hist + scan -> rs/deg, LDS-cursor CSR fill
// ===========================================================================
__global__ __launch_bounds__(256) void bhist(const int4* __restrict__ rows4,
                                             int* __restrict__ bcnt) {
    __shared__ int lcnt[NBUK];
    for (int b = threadIdx.x; b < NBUK; b += 256) lcnt[b] = 0;
    __syncthreads();
    const int q0 = blockIdx.x * (EPB / 4);
#pragma unroll
    for (int k = 0; k < EPB / 1024; ++k) {
        int q = q0 + k * 256 + threadIdx.x;
        if (q < NE / 4) {
            int4 r = rows4[q];
            atomicAdd(&lcnt[r.x >> BSHIFT], 1);
            atomicAdd(&lcnt[r.y >> BSHIFT], 1);
            atomicAdd(&lcnt[r.z >> BSHIFT], 1);
            atomicAdd(&lcnt[r.w >> BSHIFT], 1);
        }
    }
    __syncthreads();
    for (int b = threadIdx.x; b < NBUK; b += 256) {
        int c = lcnt[b];
        if (c) atomicAdd(&bcnt[b], c);
    }
}

__global__ __launch_bounds__(512) void bscan(const int* __restrict__ bcnt,
                                             int* __restrict__ bsc,
                                             int* __restrict__ gcur) {
    __shared__ int buf[512];
    int t = threadIdx.x;
    int v = (t < NBUK) ? bcnt[t] : 0;
    buf[t] = v;
    __syncthreads();
    for (int off = 1; off < 512; off <<= 1) {
        int x = (t >= off) ? buf[t - off] : 0;
        __syncthreads();
        buf[t] += x;
        __syncthreads();
    }
    if (t < NBUK) {
        int excl = buf[t] - v;
        bsc[t]  = excl;
        gcur[t] = excl;
    }
    if (t == NBUK - 1) bsc[NBUK] = buf[t];   // == NE
}

// partition: records packed {(lrow<<18)|col, val_bits}; each block reserves
// one contiguous run per bucket -> coalesced-ish writes, no hot atomics.
__global__ __launch_bounds__(256) void part_kernel(const int4* __restrict__ rows4,
                                                   const int4* __restrict__ cols4,
                                                   const float4* __restrict__ vals4,
                                                   int* __restrict__ gcur,
                                                   uint2* __restrict__ part) {
    __shared__ int lcnt[NBUK];
    __shared__ int lbase[NBUK];
    for (int b = threadIdx.x; b < NBUK; b += 256) lcnt[b] = 0;
    __syncthreads();
    const int q0 = blockIdx.x * (EPB / 4);
    int4 rc[EPB / 1024];
#pragma unroll
    for (int k = 0; k < EPB / 1024; ++k) {
        int q = q0 + k * 256 + threadIdx.x;
        if (q < NE / 4) {
            int4 r = rows4[q];
            rc[k] = r;
            atomicAdd(&lcnt[r.x >> BSHIFT], 1);
            atomicAdd(&lcnt[r.y >> BSHIFT], 1);
            atomicAdd(&lcnt[r.z >> BSHIFT], 1);
            atomicAdd(&lcnt[r.w >> BSHIFT], 1);
        } else {
            rc[k] = make_int4(-1, -1, -1, -1);
        }
    }
    __syncthreads();
    for (int b = threadIdx.x; b < NBUK; b += 256) {
        int c = lcnt[b];
        lbase[b] = c ? atomicAdd(&gcur[b], c) : 0;
        lcnt[b] = 0;                       // reset for rank assignment
    }
    __syncthreads();
#pragma unroll
    for (int k = 0; k < EPB / 1024; ++k) {
        int q = q0 + k * 256 + threadIdx.x;
        if (q < NE / 4) {
            int4   c4 = cols4[q];
            float4 v4 = vals4[q];
            int r, b, rk;
            uint2 rec;
            r = rc[k].x; b = r >> BSHIFT; rk = atomicAdd(&lcnt[b], 1);
            rec.x = ((u32)(r & (BROWS - 1)) << 18) | (u32)c4.x;
            rec.y = __float_as_uint(v4.x);  part[lbase[b] + rk] = rec;
            r = rc[k].y; b = r >> BSHIFT; rk = atomicAdd(&lcnt[b], 1);
            rec.x = ((u32)(r & (BROWS - 1)) << 18) | (u32)c4.y;
            rec.y = __float_as_uint(v4.y);  part[lbase[b] + rk] = rec;
            r = rc[k].z; b = r >> BSHIFT; rk = atomicAdd(&lcnt[b], 1);
            rec.x = ((u32)(r & (BROWS - 1)) << 18) | (u32)c4.z;
            rec.y = __float_as_uint(v4.z);  part[lbase[b] + rk] = rec;
            r = rc[k].w; b = r >> BSHIFT; rk = atomicAdd(&lcnt[b], 1);
            rec.x = ((u32)(r & (BROWS - 1)) << 18) | (u32)c4.w;
            rec.y = __float_as_uint(v4.w);  part[lbase[b] + rk] = rec;
        }
    }
}

// one block per bucket: row-hist -> LDS scan -> rs/deg, then LDS-cursor fill
__global__ __launch_bounds__(512) void bfill(const uint2* __restrict__ part,
                                             const int* __restrict__ bsc,
                                             int* __restrict__ rs,
                                             int* __restrict__ deg,
                                             uint2* __restrict__ ep) {
    __shared__ int h[BROWS];
    __shared__ int sc[BROWS];
    const int b = blockIdx.x;
    const int t = threadIdx.x;
    const int s = bsc[b];
    const int e = bsc[b + 1];
    h[t] = 0;
    __syncthreads();
    for (int i = s + t; i < e; i += 512)
        atomicAdd(&h[part[i].x >> 18], 1);
    __syncthreads();
    int v = h[t];
    sc[t] = v;
    __syncthreads();
    for (int off = 1; off < 512; off <<= 1) {
        int x = (t >= off) ? sc[t - off] : 0;
        __syncthreads();
        sc[t] += x;
        __syncthreads();
    }
    const int row = b * BROWS + t;
    if (row < N_NODES) {
        deg[row] = v;
        rs[row]  = s + sc[t];              // row_end convention
    }
    h[t] = s + sc[t] - v;                  // cursor = row_start
    __syncthreads();
    for (int i = s + t; i < e; i += 512) {
        uint2 rec = part[i];
        int lr  = rec.x >> 18;
        int pos = atomicAdd(&h[lr], 1);
        uint2 o;
        o.x = rec.x & 0x3FFFF;
        o.y = rec.y;
        ep[pos] = o;                       // bucket slice ~40 KB -> L2-local
    }
}

// ---------------------------------------------------------------------------
// init_misc = build_t0 (blocks 0..12499) + weight transpose (blocks 12500+).
// t0 = bf16(concat(ue,ee)); wt layout (ushort): wg0T@0 wb0T@4096 wg1T@8192
// wb1T@10240 wg2T@12288 wb2T@12800 (total 13312), all [n][k] k-contiguous.
// ---------------------------------------------------------------------------
__global__ __launch_bounds__(256) void init_misc(
        const float* __restrict__ ue, const float* __restrict__ ee,
        unsigned short* __restrict__ t0,
        const float* __restrict__ Wg0, const float* __restrict__ Wb0,
        const float* __restrict__ Wg1, const float* __restrict__ Wb1,
        const float* __restrict__ Wg2, const float* __restrict__ Wb2,
        unsigned short* __restrict__ wt) {
    if (blockIdx.x < T0_BLKS) {
        int i = blockIdx.x * 256 + threadIdx.x;          // float4 index
        const int uelems = N_USERS * 64 / 4;
        float4 v = (i < uelems) ? ((const float4*)ue)[i]
                                : ((const float4*)ee)[i - uelems];
        ushort4 o;
        o.x = f2bf(v.x); o.y = f2bf(v.y); o.z = f2bf(v.z); o.w = f2bf(v.w);
        ((ushort4*)t0)[i] = o;
        return;
    }
    int idx = (blockIdx.x - T0_BLKS) * 256 + threadIdx.x;
    if (idx < 4096) {                       // Wg0: 64x64
        int k = idx >> 6, n = idx & 63;
        wt[0 + n * 64 + k] = f2bf(Wg0[idx]);
    } else if (idx < 8192) {                // Wb0: 64x64
        int r = idx - 4096; int k = r >> 6, n = r & 63;
        wt[4096 + n * 64 + k] = f2bf(Wb0[r]);
    } else if (idx < 10240) {               // Wg1: 64x32
        int r = idx - 8192; int k = r >> 5, n = r & 31;
        wt[8192 + n * 64 + k] = f2bf(Wg1[r]);
    } else if (idx < 12288) {               // Wb1: 64x32
        int r = idx - 10240; int k = r >> 5, n = r & 31;
        wt[10240 + n * 64 + k] = f2bf(Wb1[r]);
    } else if (idx < 12800) {               // Wg2: 32x16
        int r = idx - 12288; int k = r >> 4, n = r & 15;
        wt[12288 + n * 32 + k] = f2bf(Wg2[r]);
    } else if (idx < 13312) {               // Wb2: 32x16
        int r = idx - 12800; int k = r >> 4, n = r & 15;
        wt[12800 + n * 32 + k] = f2bf(Wb2[r]);
    }
}

// ===========================================================================
// Fused layer: gather (wave-per-row, scalar CSR) -> LDS H/P tile -> MFMA ->
// epilogue. NEW (r5): gather loads ushort2 (4 B/lane) so one VMEM instruction
// serves 2 edges (DIN=64, half-waves) / 4 edges (DIN=32, quarter-waves);
// 8 edges in flight per wave (2x MLP, 0.5x VMEM instructions) — attacks the
// latency/request-rate bound seen in r4 (VALUBusy 34%, no pipe saturated).
// Each lane accumulates a bf16 PAIR (dims 2*d2, 2*d2+1) in float2.
// EGO: 0 = ue/ee fp32 (L0), 1 = xin fp32 (L1), 2 = tin bf16 (L2).
// mfma_f32_16x16x32_bf16: A[row=l&15][k=(l>>4)*8+j], B[k][col=l&15],
// D col=l&15, row=(l>>4)*4+reg  (layout verified rounds 1-4).
// ===========================================================================
template <int DIN, int DOUT, int EGO, int WX>
__global__ __launch_bounds__(256) void layer_fused(
        const int* __restrict__ rs, const int* __restrict__ deg,
        const uint2* __restrict__ ep,
        const unsigned short* __restrict__ tin,
        const float* __restrict__ ue, const float* __restrict__ ee,
        const float* __restrict__ xin,
        const unsigned short* __restrict__ WgT,   // bf16 [DOUT][DIN]
        const unsigned short* __restrict__ WbT,
        const float* __restrict__ bg, const float* __restrict__ bb,
        float* __restrict__ xout,                 // fp32 [N][DOUT] (if WX)
        unsigned short* __restrict__ tout,        // bf16 [N][DOUT]
        float* __restrict__ norm_out) {
    constexpr int NTC = DOUT / 16;        // col tiles per block
    constexpr int R   = (4 / NTC) * 16;   // rows per block
    constexpr int RPW = R / 4;            // rows gathered per wave
    constexpr int KS  = DIN / 32;

    __shared__ __align__(16) unsigned short sH[R * DIN];
    __shared__ __align__(16) unsigned short sP[R * DIN];
    __shared__ float sPart[R * NTC];

    const int lane    = threadIdx.x & 63;
    const int wave    = threadIdx.x >> 6;
    const int rowbase = blockIdx.x * R;

    // ---- gather phase: wave gathers its RPW rows sequentially ----
    for (int rr = 0; rr < RPW; ++rr) {
        const int lr  = wave * RPW + rr;
        const int row = __builtin_amdgcn_readfirstlane(rowbase + lr);
        const int end   = rs[row];
        const int start = end - deg[row];

        if (DIN == 64) {
            const int g  = lane >> 5;          // edge sub-slot (2 per load)
            const int d2 = lane & 31;          // bf16-pair index
            const u32* t32 = (const u32*)tin;
            float ax0 = 0.f, ay0 = 0.f, ax1 = 0.f, ay1 = 0.f;
            float ax2 = 0.f, ay2 = 0.f, ax3 = 0.f, ay3 = 0.f;
            for (int i = start; i < end; i += 8) {
                uint2 r0 = ep[i + 0], r1 = ep[i + 1], r2 = ep[i + 2], r3 = ep[i + 3];
                uint2 r4 = ep[i + 4], r5 = ep[i + 5], r6 = ep[i + 6], r7 = ep[i + 7];
                int c0 = (int)r0.x;
                int c1 = ((u32)r1.x < N_NODES) ? (int)r1.x : 0;
                int c2 = ((u32)r2.x < N_NODES) ? (int)r2.x : 0;
                int c3 = ((u32)r3.x < N_NODES) ? (int)r3.x : 0;
                int c4 = ((u32)r4.x < N_NODES) ? (int)r4.x : 0;
                int c5 = ((u32)r5.x < N_NODES) ? (int)r5.x : 0;
                int c6 = ((u32)r6.x < N_NODES) ? (int)r6.x : 0;
                int c7 = ((u32)r7.x < N_NODES) ? (int)r7.x : 0;
                float v0 = __uint_as_float(r0.y);
                float v1 = (i + 1 < end) ? __uint_as_float(r1.y) : 0.f;
                float v2 = (i + 2 < end) ? __uint_as_float(r2.y) : 0.f;
                float v3 = (i + 3 < end) ? __uint_as_float(r3.y) : 0.f;
                float v4 = (i + 4 < end) ? __uint_as_float(r4.y) : 0.f;
                float v5 = (i + 5 < end) ? __uint_as_float(r5.y) : 0.f;
                float v6 = (i + 6 < end) ? __uint_as_float(r6.y) : 0.f;
                float v7 = (i + 7 < end) ? __uint_as_float(r7.y) : 0.f;
                int   cA = g ? c1 : c0;  float vA = g ? v1 : v0;
                int   cB = g ? c3 : c2;  float vB = g ? v3 : v2;
                int   cC = g ? c5 : c4;  float vC = g ? v5 : v4;
                int   cD = g ? c7 : c6;  float vD = g ? v7 : v6;
                u32 xA = t32[(size_t)cA * 32 + d2];
                u32 xB = t32[(size_t)cB * 32 + d2];
                u32 xC = t32[(size_t)cC * 32 + d2];
                u32 xD = t32[(size_t)cD * 32 + d2];
                ax0 = fmaf(vA, bflo(xA), ax0);  ay0 = fmaf(vA, bfhi(xA), ay0);
                ax1 = fmaf(vB, bflo(xB), ax1);  ay1 = fmaf(vB, bfhi(xB), ay1);
                ax2 = fmaf(vC, bflo(xC), ax2);  ay2 = fmaf(vC, bfhi(xC), ay2);
                ax3 = fmaf(vD, bflo(xD), ax3);  ay3 = fmaf(vD, bfhi(xD), ay3);
            }
            float ax = (ax0 + ax1) + (ax2 + ax3);
            float ay = (ay0 + ay1) + (ay2 + ay3);
            ax += __shfl_xor(ax, 32);
            ay += __shfl_xor(ay, 32);

            float ex, ey;
            if (EGO == 0) {
                const float2* src = (row < N_USERS)
                    ? (const float2*)ue + (size_t)row * 32
                    : (const float2*)ee + (size_t)(row - N_USERS) * 32;
                float2 ev = src[d2];  ex = ev.x;  ey = ev.y;
            } else if (EGO == 1) {
                float2 ev = ((const float2*)xin)[(size_t)row * 32 + d2];
                ex = ev.x;  ey = ev.y;
            } else {
                u32 tv = t32[(size_t)row * 32 + d2];
                ex = bflo(tv);  ey = bfhi(tv);
            }
            if (g == 0) {
                u32 hw = ((u32)f2bf(ey + ay) << 16) | f2bf(ex + ax);
                u32 pw = ((u32)f2bf(ey * ay) << 16) | f2bf(ex * ax);
                ((u32*)sH)[lr * 32 + d2] = hw;
                ((u32*)sP)[lr * 32 + d2] = pw;
            }
        } else {   // DIN == 32: quarter-waves, 4 edges per load, unroll 2
            const int g  = lane >> 4;          // 0..3
            const int d2 = lane & 15;
            const u32* t16 = (const u32*)tin;
            float ax0 = 0.f, ay0 = 0.f, ax1 = 0.f, ay1 = 0.f;
            for (int i = start; i < end; i += 8) {
                uint2 r0 = ep[i + 0], r1 = ep[i + 1], r2 = ep[i + 2], r3 = ep[i + 3];
                uint2 r4 = ep[i + 4], r5 = ep[i + 5], r6 = ep[i + 6], r7 = ep[i + 7];
                int c0 = (int)r0.x;
                int c1 = ((u32)r1.x < N_NODES) ? (int)r1.x : 0;
                int c2 = ((u32)r2.x < N_NODES) ? (int)r2.x : 0;
                int c3 = ((u32)r3.x < N_NODES) ? (int)r3.x : 0;
                int c4 = ((u32)r4.x < N_NODES) ? (int)r4.x : 0;
                int c5 = ((u32)r5.x < N_NODES) ? (int)r5.x : 0;
                int c6 = ((u32)r6.x < N_NODES) ? (int)r6.x : 0;
                int c7 = ((u32)r7.x < N_NODES) ? (int)r7.x : 0;
                float v0 = __uint_as_float(r0.y);
                float v1 = (i + 1 < end) ? __uint_as_float(r1.y) : 0.f;
                float v2 = (i + 2 < end) ? __uint_as_float(r2.y) : 0.f;
                float v3 = (i + 3 < end) ? __uint_as_float(r3.y) : 0.f;
                float v4 = (i + 4 < end) ? __uint_as_float(r4.y) : 0.f;
                float v5 = (i + 5 < end) ? __uint_as_float(r5.y) : 0.f;
                float v6 = (i + 6 < end) ? __uint_as_float(r6.y) : 0.f;
                float v7 = (i + 7 < end) ? __uint_as_float(r7.y) : 0.f;
                int   cA = (g & 2) ? ((g & 1) ? c3 : c2) : ((g & 1) ? c1 : c0);
                float vA = (g & 2) ? ((g & 1) ? v3 : v2) : ((g & 1) ? v1 : v0);
                int   cB = (g & 2) ? ((g & 1) ? c7 : c6) : ((g & 1) ? c5 : c4);
                float vB = (g & 2) ? ((g & 1) ? v7 : v6) : ((g & 1) ? v5 : v4);
                u32 xA = t16[(size_t)cA * 16 + d2];
                u32 xB = t16[(size_t)cB * 16 + d2];
                ax0 = fmaf(vA, bflo(xA), ax0);  ay0 = fmaf(vA, bfhi(xA), ay0);
                ax1 = fmaf(vB, bflo(xB), ax1);  ay1 = fmaf(vB, bfhi(xB), ay1);
            }
            float ax = ax0 + ax1;
            float ay = ay0 + ay1;
            ax += __shfl_xor(ax, 32);  ay += __shfl_xor(ay, 32);
            ax += __shfl_xor(ax, 16);  ay += __shfl_xor(ay, 16);

            float ex, ey;
            if (EGO == 2) {
                u32 tv = t16[(size_t)row * 16 + d2];
                ex = bflo(tv);  ey = bfhi(tv);
            } else if (EGO == 1) {
                float2 ev = ((const float2*)xin)[(size_t)row * 16 + d2];
                ex = ev.x;  ey = ev.y;
            } else {
                const float2* src = (row < N_USERS)
                    ? (const float2*)ue + (size_t)row * 32
                    : (const float2*)ee + (size_t)(row - N_USERS) * 32;
                float2 ev = src[d2];  ex = ev.x;  ey = ev.y;
            }
            if (g == 0) {
                u32 hw = ((u32)f2bf(ey + ay) << 16) | f2bf(ex + ax);
                u32 pw = ((u32)f2bf(ey * ay) << 16) | f2bf(ex * ax);
                ((u32*)sH)[lr * 16 + d2] = hw;
                ((u32*)sP)[lr * 16 + d2] = pw;
            }
        }
    }
    __syncthreads();

    // ---- MFMA phase: wave (rt, ct) computes 16 rows x 16 cols ----
    const int ct  = wave % NTC;
    const int rt  = wave / NTC;
    const int r16 = lane & 15;
    const int g4  = lane >> 4;

    bf16x8 ah[KS], ap[KS];
#pragma unroll
    for (int s = 0; s < KS; ++s) {
        const int aoff = (rt * 16 + r16) * DIN + g4 * 8 + s * 32;
        ah[s] = *reinterpret_cast<const bf16x8*>(sH + aoff);
        ap[s] = *reinterpret_cast<const bf16x8*>(sP + aoff);
    }
    f32x4 accg = (f32x4){0.f, 0.f, 0.f, 0.f};
    f32x4 accb = (f32x4){0.f, 0.f, 0.f, 0.f};
#pragma unroll
    for (int s = 0; s < KS; ++s) {
        const int boff = (ct * 16 + r16) * DIN + g4 * 8 + s * 32;
        bf16x8 bgf = *reinterpret_cast<const bf16x8*>(WgT + boff);
        bf16x8 bbf = *reinterpret_cast<const bf16x8*>(WbT + boff);
        accg = __builtin_amdgcn_mfma_f32_16x16x32_bf16(ah[s], bgf, accg, 0, 0, 0);
        accb = __builtin_amdgcn_mfma_f32_16x16x32_bf16(ap[s], bbf, accb, 0, 0, 0);
    }

    // epilogue: bias + leaky + sum, stores, per-row norm partials
    const int col = ct * 16 + r16;
    const float bgv = bg[col];
    const float bbv = bb[col];
    float ss[4];
#pragma unroll
    for (int r = 0; r < 4; ++r) {
        float a = accg[r] + bgv; a = a > 0.f ? a : 0.01f * a;
        float b = accb[r] + bbv; b = b > 0.f ? b : 0.01f * b;
        float nv = a + b;
        const int row = rowbase + rt * 16 + g4 * 4 + r;
        if (WX) xout[(size_t)row * DOUT + col] = nv;
        tout[(size_t)row * DOUT + col] = f2bf(nv);
        ss[r] = nv * nv;
    }
#pragma unroll
    for (int off = 1; off < 16; off <<= 1) {
#pragma unroll
        for (int r = 0; r < 4; ++r) ss[r] += __shfl_xor(ss[r], off);
    }
    if (r16 == 0) {
#pragma unroll
        for (int r = 0; r < 4; ++r)
            sPart[(rt * 16 + g4 * 4 + r) * NTC + ct] = ss[r];
    }
    __syncthreads();
    for (int t = threadIdx.x; t < R; t += 256) {
        float s = 0.f;
#pragma unroll
        for (int j = 0; j < NTC; ++j) s += sPart[t * NTC + j];
        norm_out[rowbase + t] = fmaxf(sqrtf(s), 1e-12f);
    }
}

// ===========================================================================
// Scoring: one wave per batch element; sections 64 raw + 64 (e1 fp32) +
// 32 (t2 bf16) + 16 (t3 bf16); normalization folded as 1/(norm products).
// ===========================================================================
__global__ __launch_bounds__(256) void score_kernel(
        const int* __restrict__ users, const int* __restrict__ pos,
        const int* __restrict__ neg,
        const float* __restrict__ ue, const float* __restrict__ ee,
        const float* __restrict__ e1, const float* __restrict__ n0,
        const unsigned short* __restrict__ t2, const float* __restrict__ n1,
        const unsigned short* __restrict__ t3, const float* __restrict__ n2,
        float* __restrict__ out) {
    int gid  = blockIdx.x * 256 + threadIdx.x;
    int idx  = gid >> 6;
    int lane = gid & 63;
    if (idx >= BATCH) return;
    int u  = users[idx];
    int pe = pos[idx];
    int ne = neg[idx];
    int pn = N_USERS + pe;
    int nn = N_USERS + ne;

    float s1p = 1.0f / (n0[u] * n0[pn]);
    float s1n = 1.0f / (n0[u] * n0[nn]);
    float s2p = 1.0f / (n1[u] * n1[pn]);
    float s2n = 1.0f / (n1[u] * n1[nn]);
    float s3p = 1.0f / (n2[u] * n2[pn]);
    float s3n = 1.0f / (n2[u] * n2[nn]);

    float ap = 0.f, an = 0.f;
    {
        float xu = ue[(size_t)u * 64 + lane];
        ap += xu * ee[(size_t)pe * 64 + lane];
        an += xu * ee[(size_t)ne * 64 + lane];
    }
    {
        float xu = e1[(size_t)u * 64 + lane];
        ap += xu * e1[(size_t)pn * 64 + lane] * s1p;
        an += xu * e1[(size_t)nn * 64 + lane] * s1n;
    }
    if (lane < 32) {
        float xu = bf2f(t2[(size_t)u * 32 + lane]);
        ap += xu * bf2f(t2[(size_t)pn * 32 + lane]) * s2p;
        an += xu * bf2f(t2[(size_t)nn * 32 + lane]) * s2n;
    } else if (lane < 48) {
        int d = lane - 32;
        float xu = bf2f(t3[(size_t)u * 16 + d]);
        ap += xu * bf2f(t3[(size_t)pn * 16 + d]) * s3p;
        an += xu * bf2f(t3[(size_t)nn * 16 + d]) * s3n;
    }
#pragma unroll
    for (int off = 32; off > 0; off >>= 1) {
        ap += __shfl_xor(ap, off);
        an += __shfl_xor(an, off);
    }
    if (lane == 0) {
        out[2 * idx + 0] = ap;
        out[2 * idx + 1] = an;
    }
}

// ===========================================================================
extern "C" void kernel_launch(void* const* d_in, const int* in_sizes, int n_in,
                              void* d_out, int out_size, void* d_ws, size_t ws_size,
                              hipStream_t stream) {
    const int*   users = (const int*)d_in[0];
    const int*   pos   = (const int*)d_in[1];
    const int*   neg   = (const int*)d_in[2];
    const int*   rows  = (const int*)d_in[3];
    const int*   cols  = (const int*)d_in[4];
    const float* vals  = (const float*)d_in[5];
    const float* ue    = (const float*)d_in[6];
    const float* ee    = (const float*)d_in[7];
    const float* Wg0 = (const float*)d_in[8],  *bg0 = (const float*)d_in[9];
    const float* Wb0 = (const float*)d_in[10], *bb0 = (const float*)d_in[11];
    const float* Wg1 = (const float*)d_in[12], *bg1 = (const float*)d_in[13];
    const float* Wb1 = (const float*)d_in[14], *bb1 = (const float*)d_in[15];
    const float* Wg2 = (const float*)d_in[16], *bg2 = (const float*)d_in[17];
    const float* Wb2 = (const float*)d_in[18], *bb2 = (const float*)d_in[19];

    // workspace (~128 MB; >=192 MB proven available)
    float* e1   = (float*)d_ws;                          // N x 64 fp32 (unnorm L1 out)
    float* n0   = e1 + (size_t)N_NODES * 64;             // N
    float* n1   = n0 + N_NODES;                          // N
    float* n2   = n1 + N_NODES;                          // N
    uint2* ep   = (uint2*)(n2 + N_NODES);                // E packed {col, val}
    unsigned short* tA = (unsigned short*)(ep + NE);     // N x 64 bf16 (t0, then t2)
    unsigned short* tB = tA + (size_t)N_NODES * 64;      // N x 64 bf16 (t1)
    unsigned short* t3 = tB + (size_t)N_NODES * 64;      // N x 16 bf16 (L3 out)
    unsigned short* wt = t3 + (size_t)N_NODES * 16;      // 13312 (transposed weights)
    int* deg  = (int*)(wt + 13312);                      // N
    int* rs   = deg + N_NODES;                           // N
    int* bcnt = rs + N_NODES;                            // NBUK
    int* bsc  = bcnt + NBUK;                             // NBUK + 1
    int* gcur = bsc + NBUK + 1;                          // NBUK
    uint2* part = (uint2*)e1;                            // E records (16 MB),
                                                         // reuses e1 (free until
                                                         // layer 0 writes it)

    // ---- CSR build via bucket sort + t0 table + weight transpose ----
    hipMemsetAsync(bcnt, 0, NBUK * sizeof(int), stream);
    bhist<<<PBLK, 256, 0, stream>>>((const int4*)rows, bcnt);
    bscan<<<1, 512, 0, stream>>>(bcnt, bsc, gcur);
    part_kernel<<<PBLK, 256, 0, stream>>>((const int4*)rows, (const int4*)cols,
                                          (const float4*)vals, gcur, part);
    bfill<<<NBUK, 512, 0, stream>>>(part, bsc, rs, deg, ep);
    init_misc<<<T0_BLKS + WT_BLKS, 256, 0, stream>>>(ue, ee, tA,
                                                     Wg0, Wb0, Wg1, Wb1, Wg2, Wb2, wt);

    // ---- 3 fused layers: gather -> LDS -> MFMA -> stores + norm ----
    layer_fused<64, 64, 0, 1><<<N_NODES / 16, 256, 0, stream>>>(
        rs, deg, ep, tA, ue, ee, nullptr, wt, wt + 4096, bg0, bb0, e1, tB, n0);
    layer_fused<64, 32, 1, 0><<<N_NODES / 32, 256, 0, stream>>>(
        rs, deg, ep, tB, ue, ee, e1, wt + 8192, wt + 10240, bg1, bb1, nullptr, tA, n1);
    layer_fused<32, 16, 2, 0><<<N_NODES / 64, 256, 0, stream>>>(
        rs, deg, ep, tA, ue, ee, nullptr, wt + 12288, wt + 12800, bg2, bb2, nullptr, t3, n2);

    // ---- scoring ----
    score_kernel<<<(BATCH * 64) / 256, 256, 0, stream>>>(users, pos, neg, ue, ee,
                                                         e1, n0, tA, n1, t3, n2,
                                                         (float*)d_out);
}